// Round 9
// baseline (184.253 us; speedup 1.0000x reference)
//
#include <hip/hip_runtime.h>
#include <hip/hip_bf16.h>
#include <stdint.h>
#include <math.h>

typedef float f32x4  __attribute__((ext_vector_type(4)));
typedef float f32x16 __attribute__((ext_vector_type(16)));
typedef short s16x8  __attribute__((ext_vector_type(8)));
typedef unsigned u32x4 __attribute__((ext_vector_type(4)));

#define SEQ     2048
#define DMODEL  1024
#define MROWS   4096   // B*S
#define NHEAD   16

// ---------- helpers ----------
__device__ __forceinline__ unsigned short f2b(float x) {
    union { float f; unsigned u; } un; un.f = x;
    unsigned r = un.u + 0x7FFFu + ((un.u >> 16) & 1u);   // RNE to bf16
    return (unsigned short)(r >> 16);
}

__device__ __forceinline__ unsigned cvtpk(float lo, float hi_) {
    unsigned r;
    asm("v_cvt_pk_bf16_f32 %0, %1, %2" : "=v"(r) : "v"(lo), "v"(hi_));
    return r;
}

// raw v_exp_f32 (2^x) — avoids the OCML exp2f routine expansion
#define EXP2(x) __builtin_amdgcn_exp2f(x)

// async global->LDS, 16B per lane; LDS dest must be wave-uniform base (+lane*16 by HW)
__device__ __forceinline__ void g2l16(const void* g, void* l) {
    __builtin_amdgcn_global_load_lds(
        (const __attribute__((address_space(1))) unsigned int*)g,
        (__attribute__((address_space(3))) unsigned int*)l,
        16, 0, 0);
}

// ---------- kernel 1: f32 -> bf16 for query/key/value ----------
__global__ __launch_bounds__(256) void cvt3_kernel(
    const float* __restrict__ q, const float* __restrict__ k, const float* __restrict__ v,
    unsigned short* __restrict__ out)
{
    const float* in = blockIdx.y == 0 ? q : (blockIdx.y == 1 ? k : v);
    size_t i = ((size_t)blockIdx.x * 256 + threadIdx.x) * 4;
    float4 val = *(const float4*)(in + i);
    ushort4 o;
    o.x = f2b(val.x); o.y = f2b(val.y); o.z = f2b(val.z); o.w = f2b(val.w);
    *(ushort4*)(out + (size_t)blockIdx.y * ((size_t)MROWS * DMODEL) + i) = o;
}

// ---------- kernel 2: weight transpose + convert: wT[n][k] = bf16(w[k][n]) ----------
__global__ __launch_bounds__(256) void wtrans_kernel(
    const float* __restrict__ w0, const float* __restrict__ w1,
    const float* __restrict__ w2, const float* __restrict__ w3,
    unsigned short* __restrict__ wt)
{
    const int z = blockIdx.z;
    const float* w = z == 0 ? w0 : z == 1 ? w1 : z == 2 ? w2 : w3;
    __shared__ float t[32][33];
    const int bx = blockIdx.x * 32;   // n base
    const int by = blockIdx.y * 32;   // k base
    const int tx = threadIdx.x, ty = threadIdx.y;   // (32, 8)
    #pragma unroll
    for (int i = 0; i < 4; ++i)
        t[ty + i*8][tx] = w[(size_t)(by + ty + i*8) * DMODEL + bx + tx];  // t[krel][nrel]
    __syncthreads();
    unsigned short* o = wt + (size_t)z * ((size_t)DMODEL * DMODEL);
    #pragma unroll
    for (int i = 0; i < 4; ++i) {
        int nrel = ty + i*8, krel = tx;
        o[(size_t)(bx + nrel) * DMODEL + by + krel] = f2b(t[krel][nrel]);
    }
}

// ---------- kernel 3/5: bf16 MFMA GEMM, C = A[M,K] * Bt[N,K]^T + bias ----------
template<int TM>
__global__ __launch_bounds__(256, (TM == 128 ? 3 : 2)) void gemm_kernel(
    int mode_base,
    const unsigned short* __restrict__ xbase,
    const unsigned short* __restrict__ wtbase,
    const float* __restrict__ b0, const float* __restrict__ b1,
    const float* __restrict__ b2, const float* __restrict__ b3,
    unsigned short* __restrict__ qh, unsigned short* __restrict__ kh,
    unsigned short* __restrict__ vT, float* __restrict__ outF)
{
    constexpr int WM = TM / 2;      // wave rows
    constexpr int MT = WM / 16;     // m-tiles per wave
    const int mode = mode_base + blockIdx.z;
    const unsigned short* Ap = xbase + (size_t)(mode < 3 ? mode : 0) * ((size_t)MROWS * DMODEL);
    const unsigned short* Bt = wtbase + (size_t)mode * ((size_t)DMODEL * DMODEL);
    const float* bias = mode == 0 ? b0 : mode == 1 ? b1 : mode == 2 ? b2 : b3;

    __shared__ unsigned short As[TM * 64];
    __shared__ unsigned short Bs[128 * 64];

    const int tid = threadIdx.x;
    const int lane = tid & 63, wid = tid >> 6;
    const int ll = lane & 15, lg = lane >> 4;
    const int mb = blockIdx.x * TM, nb = blockIdx.y * 128;
    const int wr = wid >> 1, wc = wid & 1;

    f32x4 acc[MT][4] = {};

    for (int kb = 0; kb < DMODEL; kb += 64) {
        __syncthreads();
        #pragma unroll
        for (int is = 0; is < TM / 32; ++is) {     // stage A tile (TM x 64 bf16), swizzled source
            int ci = is * 256 + tid;
            int r = ci >> 3;
            int cbs = ((ci & 7) * 16) ^ ((r & 7) << 4);
            g2l16((const char*)Ap + ((size_t)(mb + r) * DMODEL + kb) * 2 + cbs,
                  (char*)As + (is * 256 + wid * 64) * 16);
        }
        #pragma unroll
        for (int is = 0; is < 4; ++is) {           // stage Bt tile (128 x 64 bf16)
            int ci = is * 256 + tid;
            int r = ci >> 3;
            int cbs = ((ci & 7) * 16) ^ ((r & 7) << 4);
            g2l16((const char*)Bt + ((size_t)(nb + r) * DMODEL + kb) * 2 + cbs,
                  (char*)Bs + (is * 256 + wid * 64) * 16);
        }
        __syncthreads();
        #pragma unroll
        for (int kk = 0; kk < 2; ++kk) {
            s16x8 af[MT], bfr[4];
            #pragma unroll
            for (int m = 0; m < MT; ++m) {
                int row = wr * WM + m * 16 + ll;
                int cbyte = (kk * 64 + lg * 16) ^ ((row & 7) << 4);
                af[m] = *(const s16x8*)((const char*)As + row * 128 + cbyte);
            }
            #pragma unroll
            for (int n = 0; n < 4; ++n) {
                int row = wc * 64 + n * 16 + ll;
                int cbyte = (kk * 64 + lg * 16) ^ ((row & 7) << 4);
                bfr[n] = *(const s16x8*)((const char*)Bs + row * 128 + cbyte);
            }
            #pragma unroll
            for (int m = 0; m < MT; ++m)
                #pragma unroll
                for (int n = 0; n < 4; ++n)
                    acc[m][n] = __builtin_amdgcn_mfma_f32_16x16x32_bf16(af[m], bfr[n], acc[m][n], 0, 0, 0);
        }
    }

    // epilogue: C/D layout col = lane&15, row = (lane>>4)*4 + r   [m89-verified]
    #pragma unroll
    for (int m = 0; m < MT; ++m) {
        int grow0 = mb + wr * WM + m * 16 + lg * 4;
        #pragma unroll
        for (int n = 0; n < 4; ++n) {
            int col = nb + wc * 64 + n * 16 + ll;
            float bc = bias[col];
            f32x4 v = acc[m][n];
            if (mode == 3) {
                #pragma unroll
                for (int r = 0; r < 4; ++r)
                    outF[(size_t)(grow0 + r) * DMODEL + col] = v[r] + bc;
            } else if (mode == 2) {
                int b = grow0 >> 11, s0 = grow0 & 2047;
                int h = col >> 6, d = col & 63;
                ushort4 pk;
                pk.x = f2b(v[0] + bc); pk.y = f2b(v[1] + bc);
                pk.z = f2b(v[2] + bc); pk.w = f2b(v[3] + bc);
                *(ushort4*)(vT + ((size_t)((b * NHEAD + h) * 64 + d) << 11) + s0) = pk;
            } else {
                unsigned short* dst = (mode == 0) ? qh : kh;
                // fold 1/sqrt(depth) * log2(e) into Q so softmax can use exp2
                float scl = (mode == 0) ? 0.125f * 1.44269504089f : 1.0f;
                int b = grow0 >> 11, s0 = grow0 & 2047;
                int h = col >> 6, d = col & 63;
                #pragma unroll
                for (int r = 0; r < 4; ++r)
                    dst[((size_t)(b * NHEAD + h) * SEQ + s0 + r) * 64 + d] = f2b((v[r] + bc) * scl);
            }
        }
    }
}

// ---------- kernel 4: causal flash attention, 2-wave 64-row blocks ----------
// grid 1024 x 128thr: block bid -> (bh = bid&31, j = 31 - bid/32), 64 q-rows,
// KVBLK=64, j+1 steps, heavy-first. K: LDS dbuf via g2l16 + XOR swizzle
// (conflict-prone column-slice pattern). V: DIRECT GLOBAL per-lane contiguous
// 16B rows (no swizzle needed; both waves share the 8KB tile via L1 — pattern
// numerics proven in R7). LDS = 16.5KB -> 10 blocks/CU = 5 waves/SIMD.
__global__ __launch_bounds__(128, 5) void attn_kernel(
    const unsigned short* __restrict__ qh, const unsigned short* __restrict__ kh,
    const unsigned short* __restrict__ vT, unsigned short* __restrict__ attnout)
{
    const int bid = blockIdx.x;
    const int bh = bid & 31;
    const int j  = 31 - (bid >> 5);     // heavy-first
    const int qb = j * 64;
    const int nsteps = j + 1;

    const unsigned short* Q = qh + (size_t)bh * (SEQ * 64);
    const unsigned short* K = kh + (size_t)bh * (SEQ * 64);
    const unsigned short* V = vT + (size_t)bh * (64 * SEQ);   // [64 d][2048 s]

    __shared__ unsigned short Ks[2][64 * 64];   // [k][d] swizzled, dbuf (8KB each)

    const int tid = threadIdx.x, lane = tid & 63, wid = tid >> 6;   // wid 0/1
    const int l31 = lane & 31, hi = lane >> 5;
    const int qrow = qb + wid * 32 + l31;
    const int swz = (l31 & 7) << 4;

    // Q B-fragments: lane holds Q[q=qrow][d = 16u + 8*hi + jj]  (pre-scaled log2e/8)
    s16x8 aq[4];
    {
        const unsigned short* qp = Q + (size_t)qrow * 64 + hi * 8;
        #pragma unroll
        for (int u = 0; u < 4; ++u)
            aq[u] = *(const s16x8*)(qp + u * 16);
    }

    f32x16 oc0 = {}, oc1 = {};     // O[q=crow(r,hi)][d]: d-halves 0..31 / 32..63
    float mrow = -1e30f, lrow = 0.f;

    // V row base for this lane: d = l31 (and +32), byte-contiguous in k
    const unsigned short* Vrow = V + (size_t)l31 * SEQ + hi * 8;

    // staging (K only): 64x128B tile = 512 slots; 128 threads x 4 iters
#define STAGE(KDST, KB)                                                                  \
    {                                                                                    \
        _Pragma("unroll")                                                                \
        for (int it = 0; it < 4; ++it) {                                                 \
            int ci = it * 128 + tid;                                                     \
            int sr = ci >> 3;                                                            \
            int sb = ((ci & 7) * 16) ^ ((sr & 7) << 4);                                  \
            int lb = (it * 128 + wid * 64) * 16;                                         \
            g2l16((const char*)K + ((size_t)((KB) + sr) * 64) * 2 + sb, (char*)(KDST) + lb); \
        }                                                                                \
    }

    STAGE(Ks[0], 0);
    __syncthreads();

    int cur = 0;
    for (int step = 0; step < nsteps; ++step) {
        const int kb = step * 64;
        if (step + 1 < nsteps)      // stage next (overlaps compute)
            STAGE(Ks[cur ^ 1], kb + 64);

        const char* KsC = (const char*)Ks[cur];

        // S^T = K . Q^T : p0 = k-rows [kb,kb+32), p1 = [kb+32,kb+64); q = l31
        f32x16 p0 = {}, p1 = {};
        __builtin_amdgcn_s_setprio(1);
        #pragma unroll
        for (int u = 0; u < 4; ++u) {
            int cb = (u * 32 + hi * 16) ^ swz;
            s16x8 k0 = *(const s16x8*)(KsC + l31 * 128 + cb);
            s16x8 k1 = *(const s16x8*)(KsC + (32 + l31) * 128 + cb);
            p0 = __builtin_amdgcn_mfma_f32_32x32x16_bf16(k0, aq[u], p0, 0, 0, 0);
            p1 = __builtin_amdgcn_mfma_f32_32x32x16_bf16(k1, aq[u], p1, 0, 0, 0);
        }
        __builtin_amdgcn_s_setprio(0);

        if (step == nsteps - 1) {   // diagonal: mask k > q
            #pragma unroll
            for (int r = 0; r < 16; ++r) {
                int rl = (r & 3) + 8 * (r >> 2) + 4 * hi;
                if (kb + rl > qrow)      p0[r] = -1e30f;
                if (kb + 32 + rl > qrow) p1[r] = -1e30f;
            }
        }

        // in-lane row max over 32 values, then cross-half
        float tm[8];
        #pragma unroll
        for (int i = 0; i < 8; ++i)
            tm[i] = fmaxf(fmaxf(p0[i], p0[i + 8]), fmaxf(p1[i], p1[i + 8]));
        float mx = fmaxf(fmaxf(fmaxf(tm[0], tm[1]), fmaxf(tm[2], tm[3])),
                         fmaxf(fmaxf(tm[4], tm[5]), fmaxf(tm[6], tm[7])));
        mx = fmaxf(mx, __shfl_xor(mx, 32, 64));

        // defer-max: only rescale when the max moved by > 8 (P <= 2^8 ok)
        if (!__all(mx - mrow <= 8.0f)) {
            float mnew = fmaxf(mrow, mx);
            float sclf = EXP2(mrow - mnew);   // factor for q-row = l31
            lrow *= sclf;
            #pragma unroll
            for (int r = 0; r < 16; ++r) {    // oc[r] is q-row crow(r,hi)
                int src = (r & 3) + 8 * (r >> 2) + 4 * hi;
                float sf = __shfl(sclf, src, 64);
                oc0[r] *= sf;
                oc1[r] *= sf;
            }
            mrow = mnew;
        }

        // exp in place (base-2 domain)
        #pragma unroll
        for (int i = 0; i < 16; ++i) { p0[i] = EXP2(p0[i] - mrow); p1[i] = EXP2(p1[i] - mrow); }

        // in-lane sum + cross-half (l state is per q-row = l31)
        float s8[8];
        #pragma unroll
        for (int i = 0; i < 8; ++i)
            s8[i] = (p0[i] + p0[i + 8]) + (p1[i] + p1[i + 8]);
        float ts = ((s8[0] + s8[1]) + (s8[2] + s8[3])) + ((s8[4] + s8[5]) + (s8[6] + s8[7]));
        ts += __shfl_xor(ts, 32, 64);
        lrow += ts;

        // P -> A-fragments: cvt_pk pairs + v_permlane32_swap cross-half exchange
        s16x8 pa[4];
        #pragma unroll
        for (int g = 0; g < 4; ++g) {
            const f32x16 pv = (g < 2) ? p0 : p1;
            const int o = (g & 1) * 8;
            unsigned a0 = cvtpk(pv[o + 0], pv[o + 1]);
            unsigned a1 = cvtpk(pv[o + 2], pv[o + 3]);
            unsigned b0 = cvtpk(pv[o + 4], pv[o + 5]);
            unsigned b1 = cvtpk(pv[o + 6], pv[o + 7]);
            asm("v_permlane32_swap_b32 %0, %1" : "+v"(a0), "+v"(b0));
            asm("v_permlane32_swap_b32 %0, %1" : "+v"(a1), "+v"(b1));
            u32x4 t4 = {a0, a1, b0, b1};
            pa[g] = __builtin_bit_cast(s16x8, t4);
        }

        // O += P V : B-frag DIRECT from global V[d][k] rows (contiguous 16B, L1-shared)
        const unsigned short* Vp = Vrow + kb;
        __builtin_amdgcn_s_setprio(1);
        #pragma unroll
        for (int s = 0; s < 4; ++s) {
            s16x8 vb0 = *(const s16x8*)(Vp + s * 16);
            s16x8 vb1 = *(const s16x8*)(Vp + 32 * SEQ + s * 16);
            oc0 = __builtin_amdgcn_mfma_f32_32x32x16_bf16(pa[s], vb0, oc0, 0, 0, 0);
            oc1 = __builtin_amdgcn_mfma_f32_32x32x16_bf16(pa[s], vb1, oc1, 0, 0, 0);
        }
        __builtin_amdgcn_s_setprio(0);

        __syncthreads();   // Ks[cur] free, Ks[cur^1] staged
        cur ^= 1;
    }
#undef STAGE

    // epilogue: per-q-row 1/l via __shfl (valid in both halves), write bf16 out
    float inv = 1.0f / lrow;
    const int b = bh >> 4, h = bh & 15;
    #pragma unroll
    for (int r = 0; r < 16; ++r) {
        int rl = (r & 3) + 8 * (r >> 2) + 4 * hi;
        float li = __shfl(inv, rl, 64);
        size_t base = ((size_t)(b * SEQ + qb + wid * 32 + rl) << 10) + h * 64;
        attnout[base + l31]      = f2b(oc0[r] * li);
        attnout[base + 32 + l31] = f2b(oc1[r] * li);
    }
}

// ---------- launch ----------
extern "C" void kernel_launch(void* const* d_in, const int* in_sizes, int n_in,
                              void* d_out, int out_size, void* d_ws, size_t ws_size,
                              hipStream_t stream) {
    const float* query = (const float*)d_in[0];
    const float* key   = (const float*)d_in[1];
    const float* value = (const float*)d_in[2];
    // d_in[3] = mask: causal, recomputed analytically
    const float* wq = (const float*)d_in[4];
    const float* bq = (const float*)d_in[5];
    const float* wk = (const float*)d_in[6];
    const float* bk = (const float*)d_in[7];
    const float* wv = (const float*)d_in[8];
    const float* bv = (const float*)d_in[9];
    const float* wo = (const float*)d_in[10];
    const float* bo = (const float*)d_in[11];
    float* out = (float*)d_out;

    char* ws = (char*)d_ws;
    unsigned short* xb  = (unsigned short*)ws;                 // [3][4096][1024] bf16; slot 0 reused as attn-out
    unsigned short* wt  = (unsigned short*)(ws + 25165824);    // [4][1024][1024] bf16 (wT: q,k,v,o)
    unsigned short* qhp = (unsigned short*)(ws + 33554432);    // [2][16][2048][64] bf16 (scaled)
    unsigned short* khp = (unsigned short*)(ws + 41943040);    // [2][16][2048][64] bf16
    unsigned short* vTp = (unsigned short*)(ws + 50331648);    // [2][16][64][2048] bf16
    // total ws use: 58,720,256 B

    cvt3_kernel<<<dim3(4096, 3), 256, 0, stream>>>(query, key, value, xb);
    wtrans_kernel<<<dim3(32, 32, 4), dim3(32, 8), 0, stream>>>(wq, wk, wv, wo, wt);
    gemm_kernel<128><<<dim3(32, 8, 3), 256, 0, stream>>>(0, xb, wt, bq, bk, bv, bo, qhp, khp, vTp, nullptr);
    attn_kernel<<<dim3(1024), 128, 0, stream>>>(qhp, khp, vTp, xb);
    gemm_kernel<64><<<dim3(64, 8, 1), 256, 0, stream>>>(3, xb, wt, bq, bk, bv, bo, qhp, khp, vTp, out);
}

// Round 10
// 126.590 us; speedup vs baseline: 1.4555x; 1.4555x over previous
//
#include <hip/hip_runtime.h>
#include <hip/hip_bf16.h>
#include <stdint.h>
#include <math.h>

typedef float f32x4  __attribute__((ext_vector_type(4)));
typedef float f32x16 __attribute__((ext_vector_type(16)));
typedef short s16x8  __attribute__((ext_vector_type(8)));
typedef unsigned u32x4 __attribute__((ext_vector_type(4)));

#define SEQ     2048
#define DMODEL  1024
#define MROWS   4096   // B*S
#define NHEAD   16

// ---------- helpers ----------
__device__ __forceinline__ unsigned short f2b(float x) {
    union { float f; unsigned u; } un; un.f = x;
    unsigned r = un.u + 0x7FFFu + ((un.u >> 16) & 1u);   // RNE to bf16
    return (unsigned short)(r >> 16);
}

__device__ __forceinline__ unsigned cvtpk(float lo, float hi_) {
    unsigned r;
    asm("v_cvt_pk_bf16_f32 %0, %1, %2" : "=v"(r) : "v"(lo), "v"(hi_));
    return r;
}

// raw v_exp_f32 (2^x) — avoids the OCML exp2f routine expansion
#define EXP2(x) __builtin_amdgcn_exp2f(x)

// async global->LDS, 16B per lane; LDS dest must be wave-uniform base (+lane*16 by HW)
__device__ __forceinline__ void g2l16(const void* g, void* l) {
    __builtin_amdgcn_global_load_lds(
        (const __attribute__((address_space(1))) unsigned int*)g,
        (__attribute__((address_space(3))) unsigned int*)l,
        16, 0, 0);
}

// ---------- kernel 1: f32 -> bf16 for query/key/value ----------
__global__ __launch_bounds__(256) void cvt3_kernel(
    const float* __restrict__ q, const float* __restrict__ k, const float* __restrict__ v,
    unsigned short* __restrict__ out)
{
    const float* in = blockIdx.y == 0 ? q : (blockIdx.y == 1 ? k : v);
    size_t i = ((size_t)blockIdx.x * 256 + threadIdx.x) * 4;
    float4 val = *(const float4*)(in + i);
    ushort4 o;
    o.x = f2b(val.x); o.y = f2b(val.y); o.z = f2b(val.z); o.w = f2b(val.w);
    *(ushort4*)(out + (size_t)blockIdx.y * ((size_t)MROWS * DMODEL) + i) = o;
}

// ---------- kernel 2: weight transpose + convert: wT[n][k] = bf16(w[k][n]) ----------
__global__ __launch_bounds__(256) void wtrans_kernel(
    const float* __restrict__ w0, const float* __restrict__ w1,
    const float* __restrict__ w2, const float* __restrict__ w3,
    unsigned short* __restrict__ wt)
{
    const int z = blockIdx.z;
    const float* w = z == 0 ? w0 : z == 1 ? w1 : z == 2 ? w2 : w3;
    __shared__ float t[32][33];
    const int bx = blockIdx.x * 32;   // n base
    const int by = blockIdx.y * 32;   // k base
    const int tx = threadIdx.x, ty = threadIdx.y;   // (32, 8)
    #pragma unroll
    for (int i = 0; i < 4; ++i)
        t[ty + i*8][tx] = w[(size_t)(by + ty + i*8) * DMODEL + bx + tx];  // t[krel][nrel]
    __syncthreads();
    unsigned short* o = wt + (size_t)z * ((size_t)DMODEL * DMODEL);
    #pragma unroll
    for (int i = 0; i < 4; ++i) {
        int nrel = ty + i*8, krel = tx;
        o[(size_t)(bx + nrel) * DMODEL + by + krel] = f2b(t[krel][nrel]);
    }
}

// ---------- kernel 3/5: bf16 MFMA GEMM, C = A[M,K] * Bt[N,K]^T + bias ----------
template<int TM>
__global__ __launch_bounds__(256, (TM == 128 ? 3 : 2)) void gemm_kernel(
    int mode_base,
    const unsigned short* __restrict__ xbase,
    const unsigned short* __restrict__ wtbase,
    const float* __restrict__ b0, const float* __restrict__ b1,
    const float* __restrict__ b2, const float* __restrict__ b3,
    unsigned short* __restrict__ qh, unsigned short* __restrict__ kh,
    unsigned short* __restrict__ vT, float* __restrict__ outF)
{
    constexpr int WM = TM / 2;      // wave rows
    constexpr int MT = WM / 16;     // m-tiles per wave
    const int mode = mode_base + blockIdx.z;
    const unsigned short* Ap = xbase + (size_t)(mode < 3 ? mode : 0) * ((size_t)MROWS * DMODEL);
    const unsigned short* Bt = wtbase + (size_t)mode * ((size_t)DMODEL * DMODEL);
    const float* bias = mode == 0 ? b0 : mode == 1 ? b1 : mode == 2 ? b2 : b3;

    __shared__ unsigned short As[TM * 64];
    __shared__ unsigned short Bs[128 * 64];

    const int tid = threadIdx.x;
    const int lane = tid & 63, wid = tid >> 6;
    const int ll = lane & 15, lg = lane >> 4;
    const int mb = blockIdx.x * TM, nb = blockIdx.y * 128;
    const int wr = wid >> 1, wc = wid & 1;

    f32x4 acc[MT][4] = {};

    for (int kb = 0; kb < DMODEL; kb += 64) {
        __syncthreads();
        #pragma unroll
        for (int is = 0; is < TM / 32; ++is) {     // stage A tile (TM x 64 bf16), swizzled source
            int ci = is * 256 + tid;
            int r = ci >> 3;
            int cbs = ((ci & 7) * 16) ^ ((r & 7) << 4);
            g2l16((const char*)Ap + ((size_t)(mb + r) * DMODEL + kb) * 2 + cbs,
                  (char*)As + (is * 256 + wid * 64) * 16);
        }
        #pragma unroll
        for (int is = 0; is < 4; ++is) {           // stage Bt tile (128 x 64 bf16)
            int ci = is * 256 + tid;
            int r = ci >> 3;
            int cbs = ((ci & 7) * 16) ^ ((r & 7) << 4);
            g2l16((const char*)Bt + ((size_t)(nb + r) * DMODEL + kb) * 2 + cbs,
                  (char*)Bs + (is * 256 + wid * 64) * 16);
        }
        __syncthreads();
        #pragma unroll
        for (int kk = 0; kk < 2; ++kk) {
            s16x8 af[MT], bfr[4];
            #pragma unroll
            for (int m = 0; m < MT; ++m) {
                int row = wr * WM + m * 16 + ll;
                int cbyte = (kk * 64 + lg * 16) ^ ((row & 7) << 4);
                af[m] = *(const s16x8*)((const char*)As + row * 128 + cbyte);
            }
            #pragma unroll
            for (int n = 0; n < 4; ++n) {
                int row = wc * 64 + n * 16 + ll;
                int cbyte = (kk * 64 + lg * 16) ^ ((row & 7) << 4);
                bfr[n] = *(const s16x8*)((const char*)Bs + row * 128 + cbyte);
            }
            #pragma unroll
            for (int m = 0; m < MT; ++m)
                #pragma unroll
                for (int n = 0; n < 4; ++n)
                    acc[m][n] = __builtin_amdgcn_mfma_f32_16x16x32_bf16(af[m], bfr[n], acc[m][n], 0, 0, 0);
        }
    }

    // epilogue: C/D layout col = lane&15, row = (lane>>4)*4 + r   [m89-verified]
    #pragma unroll
    for (int m = 0; m < MT; ++m) {
        int grow0 = mb + wr * WM + m * 16 + lg * 4;
        #pragma unroll
        for (int n = 0; n < 4; ++n) {
            int col = nb + wc * 64 + n * 16 + ll;
            float bc = bias[col];
            f32x4 v = acc[m][n];
            if (mode == 3) {
                #pragma unroll
                for (int r = 0; r < 4; ++r)
                    outF[(size_t)(grow0 + r) * DMODEL + col] = v[r] + bc;
            } else if (mode == 2) {
                int b = grow0 >> 11, s0 = grow0 & 2047;
                int h = col >> 6, d = col & 63;
                ushort4 pk;
                pk.x = f2b(v[0] + bc); pk.y = f2b(v[1] + bc);
                pk.z = f2b(v[2] + bc); pk.w = f2b(v[3] + bc);
                *(ushort4*)(vT + ((size_t)((b * NHEAD + h) * 64 + d) << 11) + s0) = pk;
            } else {
                unsigned short* dst = (mode == 0) ? qh : kh;
                // fold 1/sqrt(depth) * log2(e) into Q so softmax can use exp2
                float scl = (mode == 0) ? 0.125f * 1.44269504089f : 1.0f;
                int b = grow0 >> 11, s0 = grow0 & 2047;
                int h = col >> 6, d = col & 63;
                #pragma unroll
                for (int r = 0; r < 4; ++r)
                    dst[((size_t)(b * NHEAD + h) * SEQ + s0 + r) * 64 + d] = f2b((v[r] + bc) * scl);
            }
        }
    }
}

// ---------- kernel 4: causal flash attention, 2-wave 64-row blocks ----------
// grid 1024 x 128thr: block bid -> (bh = bid&31, j = 31 - bid/32), 64 q-rows,
// KVBLK=64, j+1 steps, heavy-first. K: LDS dbuf via g2l16 + XOR swizzle.
// V: direct global per-lane contiguous 16B rows (L1-shared across waves).
// launch_bounds (128,4): VGPR cap 128 — R9's (128,5) cap=102 SPILLED the
// f32x16 accumulators (VGPR_Count 48, WRITE_SIZE 3x, MfmaUtil 0.3%).
__global__ __launch_bounds__(128, 4) void attn_kernel(
    const unsigned short* __restrict__ qh, const unsigned short* __restrict__ kh,
    const unsigned short* __restrict__ vT, unsigned short* __restrict__ attnout)
{
    const int bid = blockIdx.x;
    const int bh = bid & 31;
    const int j  = 31 - (bid >> 5);     // heavy-first
    const int qb = j * 64;
    const int nsteps = j + 1;

    const unsigned short* Q = qh + (size_t)bh * (SEQ * 64);
    const unsigned short* K = kh + (size_t)bh * (SEQ * 64);
    const unsigned short* V = vT + (size_t)bh * (64 * SEQ);   // [64 d][2048 s]

    __shared__ unsigned short Ks[2][64 * 64];   // [k][d] swizzled, dbuf (8KB each)

    const int tid = threadIdx.x, lane = tid & 63, wid = tid >> 6;   // wid 0/1
    const int l31 = lane & 31, hi = lane >> 5;
    const int qrow = qb + wid * 32 + l31;
    const int swz = (l31 & 7) << 4;

    // Q B-fragments: lane holds Q[q=qrow][d = 16u + 8*hi + jj]  (pre-scaled log2e/8)
    s16x8 aq[4];
    {
        const unsigned short* qp = Q + (size_t)qrow * 64 + hi * 8;
        #pragma unroll
        for (int u = 0; u < 4; ++u)
            aq[u] = *(const s16x8*)(qp + u * 16);
    }

    f32x16 oc0 = {}, oc1 = {};     // O[q=crow(r,hi)][d]: d-halves 0..31 / 32..63
    float mrow = -1e30f, lrow = 0.f;

    // V row base for this lane: d = l31 (and +32), byte-contiguous in k
    const unsigned short* Vrow = V + (size_t)l31 * SEQ + hi * 8;

    // staging (K only): 64x128B tile = 512 slots; 128 threads x 4 iters
#define STAGE(KDST, KB)                                                                  \
    {                                                                                    \
        _Pragma("unroll")                                                                \
        for (int it = 0; it < 4; ++it) {                                                 \
            int ci = it * 128 + tid;                                                     \
            int sr = ci >> 3;                                                            \
            int sb = ((ci & 7) * 16) ^ ((sr & 7) << 4);                                  \
            int lb = (it * 128 + wid * 64) * 16;                                         \
            g2l16((const char*)K + ((size_t)((KB) + sr) * 64) * 2 + sb, (char*)(KDST) + lb); \
        }                                                                                \
    }

    STAGE(Ks[0], 0);
    __syncthreads();

    int cur = 0;
    for (int step = 0; step < nsteps; ++step) {
        const int kb = step * 64;
        if (step + 1 < nsteps)      // stage next (overlaps compute)
            STAGE(Ks[cur ^ 1], kb + 64);

        const char* KsC = (const char*)Ks[cur];

        // S^T = K . Q^T : p0 = k-rows [kb,kb+32), p1 = [kb+32,kb+64); q = l31
        f32x16 p0 = {}, p1 = {};
        __builtin_amdgcn_s_setprio(1);
        #pragma unroll
        for (int u = 0; u < 4; ++u) {
            int cb = (u * 32 + hi * 16) ^ swz;
            s16x8 k0 = *(const s16x8*)(KsC + l31 * 128 + cb);
            s16x8 k1 = *(const s16x8*)(KsC + (32 + l31) * 128 + cb);
            p0 = __builtin_amdgcn_mfma_f32_32x32x16_bf16(k0, aq[u], p0, 0, 0, 0);
            p1 = __builtin_amdgcn_mfma_f32_32x32x16_bf16(k1, aq[u], p1, 0, 0, 0);
        }
        __builtin_amdgcn_s_setprio(0);

        if (step == nsteps - 1) {   // diagonal: mask k > q
            #pragma unroll
            for (int r = 0; r < 16; ++r) {
                int rl = (r & 3) + 8 * (r >> 2) + 4 * hi;
                if (kb + rl > qrow)      p0[r] = -1e30f;
                if (kb + 32 + rl > qrow) p1[r] = -1e30f;
            }
        }

        // in-lane row max over 32 values, then cross-half
        float tm[8];
        #pragma unroll
        for (int i = 0; i < 8; ++i)
            tm[i] = fmaxf(fmaxf(p0[i], p0[i + 8]), fmaxf(p1[i], p1[i + 8]));
        float mx = fmaxf(fmaxf(fmaxf(tm[0], tm[1]), fmaxf(tm[2], tm[3])),
                         fmaxf(fmaxf(tm[4], tm[5]), fmaxf(tm[6], tm[7])));
        mx = fmaxf(mx, __shfl_xor(mx, 32, 64));

        // defer-max: only rescale when the max moved by > 8 (P <= 2^8 ok)
        if (!__all(mx - mrow <= 8.0f)) {
            float mnew = fmaxf(mrow, mx);
            float sclf = EXP2(mrow - mnew);   // factor for q-row = l31
            lrow *= sclf;
            #pragma unroll
            for (int r = 0; r < 16; ++r) {    // oc[r] is q-row crow(r,hi)
                int src = (r & 3) + 8 * (r >> 2) + 4 * hi;
                float sf = __shfl(sclf, src, 64);
                oc0[r] *= sf;
                oc1[r] *= sf;
            }
            mrow = mnew;
        }

        // exp in place (base-2 domain)
        #pragma unroll
        for (int i = 0; i < 16; ++i) { p0[i] = EXP2(p0[i] - mrow); p1[i] = EXP2(p1[i] - mrow); }

        // in-lane sum + cross-half (l state is per q-row = l31)
        float s8[8];
        #pragma unroll
        for (int i = 0; i < 8; ++i)
            s8[i] = (p0[i] + p0[i + 8]) + (p1[i] + p1[i + 8]);
        float ts = ((s8[0] + s8[1]) + (s8[2] + s8[3])) + ((s8[4] + s8[5]) + (s8[6] + s8[7]));
        ts += __shfl_xor(ts, 32, 64);
        lrow += ts;

        // P -> A-fragments: cvt_pk pairs + v_permlane32_swap cross-half exchange
        s16x8 pa[4];
        #pragma unroll
        for (int g = 0; g < 4; ++g) {
            const f32x16 pv = (g < 2) ? p0 : p1;
            const int o = (g & 1) * 8;
            unsigned a0 = cvtpk(pv[o + 0], pv[o + 1]);
            unsigned a1 = cvtpk(pv[o + 2], pv[o + 3]);
            unsigned b0 = cvtpk(pv[o + 4], pv[o + 5]);
            unsigned b1 = cvtpk(pv[o + 6], pv[o + 7]);
            asm("v_permlane32_swap_b32 %0, %1" : "+v"(a0), "+v"(b0));
            asm("v_permlane32_swap_b32 %0, %1" : "+v"(a1), "+v"(b1));
            u32x4 t4 = {a0, a1, b0, b1};
            pa[g] = __builtin_bit_cast(s16x8, t4);
        }

        // O += P V : B-frag DIRECT from global V[d][k] rows (contiguous 16B, L1-shared)
        const unsigned short* Vp = Vrow + kb;
        __builtin_amdgcn_s_setprio(1);
        #pragma unroll
        for (int s = 0; s < 4; ++s) {
            s16x8 vb0 = *(const s16x8*)(Vp + s * 16);
            s16x8 vb1 = *(const s16x8*)(Vp + 32 * SEQ + s * 16);
            oc0 = __builtin_amdgcn_mfma_f32_32x32x16_bf16(pa[s], vb0, oc0, 0, 0, 0);
            oc1 = __builtin_amdgcn_mfma_f32_32x32x16_bf16(pa[s], vb1, oc1, 0, 0, 0);
        }
        __builtin_amdgcn_s_setprio(0);

        __syncthreads();   // Ks[cur] free, Ks[cur^1] staged
        cur ^= 1;
    }
#undef STAGE

    // epilogue: per-q-row 1/l via __shfl (valid in both halves), write bf16 out
    float inv = 1.0f / lrow;
    const int b = bh >> 4, h = bh & 15;
    #pragma unroll
    for (int r = 0; r < 16; ++r) {
        int rl = (r & 3) + 8 * (r >> 2) + 4 * hi;
        float li = __shfl(inv, rl, 64);
        size_t base = ((size_t)(b * SEQ + qb + wid * 32 + rl) << 10) + h * 64;
        attnout[base + l31]      = f2b(oc0[r] * li);
        attnout[base + 32 + l31] = f2b(oc1[r] * li);
    }
}

// ---------- launch ----------
extern "C" void kernel_launch(void* const* d_in, const int* in_sizes, int n_in,
                              void* d_out, int out_size, void* d_ws, size_t ws_size,
                              hipStream_t stream) {
    const float* query = (const float*)d_in[0];
    const float* key   = (const float*)d_in[1];
    const float* value = (const float*)d_in[2];
    // d_in[3] = mask: causal, recomputed analytically
    const float* wq = (const float*)d_in[4];
    const float* bq = (const float*)d_in[5];
    const float* wk = (const float*)d_in[6];
    const float* bk = (const float*)d_in[7];
    const float* wv = (const float*)d_in[8];
    const float* bv = (const float*)d_in[9];
    const float* wo = (const float*)d_in[10];
    const float* bo = (const float*)d_in[11];
    float* out = (float*)d_out;

    char* ws = (char*)d_ws;
    unsigned short* xb  = (unsigned short*)ws;                 // [3][4096][1024] bf16; slot 0 reused as attn-out
    unsigned short* wt  = (unsigned short*)(ws + 25165824);    // [4][1024][1024] bf16 (wT: q,k,v,o)
    unsigned short* qhp = (unsigned short*)(ws + 33554432);    // [2][16][2048][64] bf16 (scaled)
    unsigned short* khp = (unsigned short*)(ws + 41943040);    // [2][16][2048][64] bf16
    unsigned short* vTp = (unsigned short*)(ws + 50331648);    // [2][16][64][2048] bf16
    // total ws use: 58,720,256 B

    cvt3_kernel<<<dim3(4096, 3), 256, 0, stream>>>(query, key, value, xb);
    wtrans_kernel<<<dim3(32, 32, 4), dim3(32, 8), 0, stream>>>(wq, wk, wv, wo, wt);
    gemm_kernel<128><<<dim3(32, 8, 3), 256, 0, stream>>>(0, xb, wt, bq, bk, bv, bo, qhp, khp, vTp, nullptr);
    attn_kernel<<<dim3(1024), 128, 0, stream>>>(qhp, khp, vTp, xb);
    gemm_kernel<64><<<dim3(64, 8, 1), 256, 0, stream>>>(3, xb, wt, bq, bk, bv, bo, qhp, khp, vTp, out);
}

// Round 11
// 110.807 us; speedup vs baseline: 1.6628x; 1.1424x over previous
//
#include <hip/hip_runtime.h>
#include <hip/hip_bf16.h>
#include <stdint.h>
#include <math.h>

typedef float f32x4  __attribute__((ext_vector_type(4)));
typedef float f32x16 __attribute__((ext_vector_type(16)));
typedef short s16x8  __attribute__((ext_vector_type(8)));
typedef unsigned u32x4 __attribute__((ext_vector_type(4)));

#define SEQ     2048
#define DMODEL  1024
#define MROWS   4096   // B*S
#define NHEAD   16

// ---------- helpers ----------
__device__ __forceinline__ unsigned short f2b(float x) {
    union { float f; unsigned u; } un; un.f = x;
    unsigned r = un.u + 0x7FFFu + ((un.u >> 16) & 1u);   // RNE to bf16
    return (unsigned short)(r >> 16);
}

__device__ __forceinline__ unsigned cvtpk(float lo, float hi_) {
    unsigned r;
    asm("v_cvt_pk_bf16_f32 %0, %1, %2" : "=v"(r) : "v"(lo), "v"(hi_));
    return r;
}

// raw v_exp_f32 (2^x) — avoids the OCML exp2f routine expansion
#define EXP2(x) __builtin_amdgcn_exp2f(x)

// async global->LDS, 16B per lane; LDS dest must be wave-uniform base (+lane*16 by HW)
__device__ __forceinline__ void g2l16(const void* g, void* l) {
    __builtin_amdgcn_global_load_lds(
        (const __attribute__((address_space(1))) unsigned int*)g,
        (__attribute__((address_space(3))) unsigned int*)l,
        16, 0, 0);
}

// ---------- kernel 1: f32 -> bf16 for query/key/value ----------
__global__ __launch_bounds__(256) void cvt3_kernel(
    const float* __restrict__ q, const float* __restrict__ k, const float* __restrict__ v,
    unsigned short* __restrict__ out)
{
    const float* in = blockIdx.y == 0 ? q : (blockIdx.y == 1 ? k : v);
    size_t i = ((size_t)blockIdx.x * 256 + threadIdx.x) * 4;
    float4 val = *(const float4*)(in + i);
    ushort4 o;
    o.x = f2b(val.x); o.y = f2b(val.y); o.z = f2b(val.z); o.w = f2b(val.w);
    *(ushort4*)(out + (size_t)blockIdx.y * ((size_t)MROWS * DMODEL) + i) = o;
}

// ---------- kernel 2: weight transpose + convert: wT[n][k] = bf16(w[k][n]) ----------
__global__ __launch_bounds__(256) void wtrans_kernel(
    const float* __restrict__ w0, const float* __restrict__ w1,
    const float* __restrict__ w2, const float* __restrict__ w3,
    unsigned short* __restrict__ wt)
{
    const int z = blockIdx.z;
    const float* w = z == 0 ? w0 : z == 1 ? w1 : z == 2 ? w2 : w3;
    __shared__ float t[32][33];
    const int bx = blockIdx.x * 32;   // n base
    const int by = blockIdx.y * 32;   // k base
    const int tx = threadIdx.x, ty = threadIdx.y;   // (32, 8)
    #pragma unroll
    for (int i = 0; i < 4; ++i)
        t[ty + i*8][tx] = w[(size_t)(by + ty + i*8) * DMODEL + bx + tx];  // t[krel][nrel]
    __syncthreads();
    unsigned short* o = wt + (size_t)z * ((size_t)DMODEL * DMODEL);
    #pragma unroll
    for (int i = 0; i < 4; ++i) {
        int nrel = ty + i*8, krel = tx;
        o[(size_t)(bx + nrel) * DMODEL + by + krel] = f2b(t[krel][nrel]);
    }
}

// ---------- kernel 3/5: bf16 MFMA GEMM, C = A[M,K] * Bt[N,K]^T + bias ----------
template<int TM>
__global__ __launch_bounds__(256, (TM == 128 ? 3 : 2)) void gemm_kernel(
    int mode_base,
    const unsigned short* __restrict__ xbase,
    const unsigned short* __restrict__ wtbase,
    const float* __restrict__ b0, const float* __restrict__ b1,
    const float* __restrict__ b2, const float* __restrict__ b3,
    unsigned short* __restrict__ qh, unsigned short* __restrict__ kh,
    unsigned short* __restrict__ vT, float* __restrict__ outF)
{
    constexpr int WM = TM / 2;      // wave rows
    constexpr int MT = WM / 16;     // m-tiles per wave
    const int mode = mode_base + blockIdx.z;
    const unsigned short* Ap = xbase + (size_t)(mode < 3 ? mode : 0) * ((size_t)MROWS * DMODEL);
    const unsigned short* Bt = wtbase + (size_t)mode * ((size_t)DMODEL * DMODEL);
    const float* bias = mode == 0 ? b0 : mode == 1 ? b1 : mode == 2 ? b2 : b3;

    __shared__ unsigned short As[TM * 64];
    __shared__ unsigned short Bs[128 * 64];

    const int tid = threadIdx.x;
    const int lane = tid & 63, wid = tid >> 6;
    const int ll = lane & 15, lg = lane >> 4;
    const int mb = blockIdx.x * TM, nb = blockIdx.y * 128;
    const int wr = wid >> 1, wc = wid & 1;

    f32x4 acc[MT][4] = {};

    for (int kb = 0; kb < DMODEL; kb += 64) {
        __syncthreads();
        #pragma unroll
        for (int is = 0; is < TM / 32; ++is) {     // stage A tile (TM x 64 bf16), swizzled source
            int ci = is * 256 + tid;
            int r = ci >> 3;
            int cbs = ((ci & 7) * 16) ^ ((r & 7) << 4);
            g2l16((const char*)Ap + ((size_t)(mb + r) * DMODEL + kb) * 2 + cbs,
                  (char*)As + (is * 256 + wid * 64) * 16);
        }
        #pragma unroll
        for (int is = 0; is < 4; ++is) {           // stage Bt tile (128 x 64 bf16)
            int ci = is * 256 + tid;
            int r = ci >> 3;
            int cbs = ((ci & 7) * 16) ^ ((r & 7) << 4);
            g2l16((const char*)Bt + ((size_t)(nb + r) * DMODEL + kb) * 2 + cbs,
                  (char*)Bs + (is * 256 + wid * 64) * 16);
        }
        __syncthreads();
        #pragma unroll
        for (int kk = 0; kk < 2; ++kk) {
            s16x8 af[MT], bfr[4];
            #pragma unroll
            for (int m = 0; m < MT; ++m) {
                int row = wr * WM + m * 16 + ll;
                int cbyte = (kk * 64 + lg * 16) ^ ((row & 7) << 4);
                af[m] = *(const s16x8*)((const char*)As + row * 128 + cbyte);
            }
            #pragma unroll
            for (int n = 0; n < 4; ++n) {
                int row = wc * 64 + n * 16 + ll;
                int cbyte = (kk * 64 + lg * 16) ^ ((row & 7) << 4);
                bfr[n] = *(const s16x8*)((const char*)Bs + row * 128 + cbyte);
            }
            #pragma unroll
            for (int m = 0; m < MT; ++m)
                #pragma unroll
                for (int n = 0; n < 4; ++n)
                    acc[m][n] = __builtin_amdgcn_mfma_f32_16x16x32_bf16(af[m], bfr[n], acc[m][n], 0, 0, 0);
        }
    }

    // epilogue: C/D layout col = lane&15, row = (lane>>4)*4 + r   [m89-verified]
    #pragma unroll
    for (int m = 0; m < MT; ++m) {
        int grow0 = mb + wr * WM + m * 16 + lg * 4;
        #pragma unroll
        for (int n = 0; n < 4; ++n) {
            int col = nb + wc * 64 + n * 16 + ll;
            float bc = bias[col];
            f32x4 v = acc[m][n];
            if (mode == 3) {
                #pragma unroll
                for (int r = 0; r < 4; ++r)
                    outF[(size_t)(grow0 + r) * DMODEL + col] = v[r] + bc;
            } else if (mode == 2) {
                int b = grow0 >> 11, s0 = grow0 & 2047;
                int h = col >> 6, d = col & 63;
                ushort4 pk;
                pk.x = f2b(v[0] + bc); pk.y = f2b(v[1] + bc);
                pk.z = f2b(v[2] + bc); pk.w = f2b(v[3] + bc);
                *(ushort4*)(vT + ((size_t)((b * NHEAD + h) * 64 + d) << 11) + s0) = pk;
            } else {
                unsigned short* dst = (mode == 0) ? qh : kh;
                // fold 1/sqrt(depth) * log2(e) into Q so softmax can use exp2
                float scl = (mode == 0) ? 0.125f * 1.44269504089f : 1.0f;
                int b = grow0 >> 11, s0 = grow0 & 2047;
                int h = col >> 6, d = col & 63;
                #pragma unroll
                for (int r = 0; r < 4; ++r)
                    dst[((size_t)(b * NHEAD + h) * SEQ + s0 + r) * 64 + d] = f2b((v[r] + bc) * scl);
            }
        }
    }
}

// ---------- kernel 4: causal flash attention, 4-wave k-split blocks ----------
// grid 1024 x 256thr: block bid -> (bh = bid&31, j = 31 - bid/32) = 64 q-rows,
// ceil((j+1)/2) super-steps of 128 k-cols. Wave wid: qhalf = wid&1 (rows
// qb+32*qhalf..), parity = wid>>1 (64-col half of super-tile). 4096 waves
// total = 4/SIMD (vs 2048 = 2/SIMD before: q-parallelism was exhausted;
// this adds k-parallelism). K+V single-buffered in LDS (32KB, 4 blk/CU);
// cross-parity (m,l,O) merge through LDS at the end (exact flash algebra:
// the exp2(m-M) weight zeroes the j=0 empty-parity case).
__global__ __launch_bounds__(256, 4) void attn_kernel(
    const unsigned short* __restrict__ qh, const unsigned short* __restrict__ kh,
    const unsigned short* __restrict__ vT, unsigned short* __restrict__ attnout)
{
    const int bid = blockIdx.x;
    const int bh = bid & 31;
    const int j  = 31 - (bid >> 5);     // heavy-first (LPT)
    const int qb = j * 64;
    const int nss = (j >> 1) + 1;       // super-steps of 128 cols

    const unsigned short* Q = qh + (size_t)bh * (SEQ * 64);
    const unsigned short* K = kh + (size_t)bh * (SEQ * 64);
    const unsigned short* V = vT + (size_t)bh * (64 * SEQ);   // [64 d][2048 s]

    __shared__ char lds[32768];
    char* Kb = lds;            // K super-tile [128 k][64 d], 128B rows, swz (k&7)<<4
    char* Vb = lds + 16384;    // V super-tile [64 d][128 k], 256B rows, swz (d&15)<<4

    const int tid = threadIdx.x, lane = tid & 63, wid = tid >> 6;
    const int l31 = lane & 31, hi = lane >> 5;
    const int qhf = wid & 1;            // q-half
    const int par = wid >> 1;           // k-parity (col half)
    const int qrow = qb + qhf * 32 + l31;
    const int swz = (l31 & 7) << 4;

    // Q B-fragments: lane holds Q[q=qrow][d = 16u + 8*hi + jj]  (pre-scaled log2e/8)
    s16x8 aq[4];
    {
        const unsigned short* qp = Q + (size_t)qrow * 64 + hi * 8;
        #pragma unroll
        for (int u = 0; u < 4; ++u)
            aq[u] = *(const s16x8*)(qp + u * 16);
    }

    f32x16 oc0 = {}, oc1 = {};     // O[q=crow(r,hi)][d]: d-halves 0..31 / 32..63
    float mrow = -1e30f, lrow = 0.f;

    for (int ss = 0; ss < nss; ++ss) {
        const int kb = ss * 128;
        __syncthreads();               // previous compute done, LDS reusable
        #pragma unroll
        for (int it = 0; it < 4; ++it) {   // stage K: 128 rows x 128B
            int ci = it * 256 + tid;
            int r = ci >> 3;
            int sb = ((ci & 7) * 16) ^ ((r & 7) << 4);
            g2l16((const char*)K + ((size_t)(kb + r) * 64) * 2 + sb,
                  Kb + (it * 256 + wid * 64) * 16);
        }
        #pragma unroll
        for (int it = 0; it < 4; ++it) {   // stage V: 64 rows x 256B
            int ci = it * 256 + tid;
            int d = ci >> 4;
            int sb = ((ci & 15) * 16) ^ ((d & 15) << 4);
            g2l16((const char*)V + (size_t)d * (SEQ * 2) + (size_t)kb * 2 + sb,
                  Vb + (it * 256 + wid * 64) * 16);
        }
        __syncthreads();               // staged (vmcnt drained before barrier)

        // S^T = K . Q^T on this wave's 64-col half: rows par*64 + [0,64)
        const int rb = par * 64;
        f32x16 p0 = {}, p1 = {};
        __builtin_amdgcn_s_setprio(1);
        #pragma unroll
        for (int u = 0; u < 4; ++u) {
            int r0 = rb + l31, r1 = rb + 32 + l31;
            s16x8 k0 = *(const s16x8*)(Kb + r0 * 128 + (((u * 32 + hi * 16)) ^ ((r0 & 7) << 4)));
            s16x8 k1 = *(const s16x8*)(Kb + r1 * 128 + (((u * 32 + hi * 16)) ^ ((r1 & 7) << 4)));
            p0 = __builtin_amdgcn_mfma_f32_32x32x16_bf16(k0, aq[u], p0, 0, 0, 0);
            p1 = __builtin_amdgcn_mfma_f32_32x32x16_bf16(k1, aq[u], p1, 0, 0, 0);
        }
        __builtin_amdgcn_s_setprio(0);

        if (ss == nss - 1) {           // diagonal super-step: mask k > q
            const int pabs = kb + rb;
            #pragma unroll
            for (int r = 0; r < 16; ++r) {
                int rl = (r & 3) + 8 * (r >> 2) + 4 * hi;
                if (pabs + rl > qrow)      p0[r] = -1e30f;
                if (pabs + 32 + rl > qrow) p1[r] = -1e30f;
            }
        }

        // in-lane row max over 32 values, then cross-half
        float tm[8];
        #pragma unroll
        for (int i = 0; i < 8; ++i)
            tm[i] = fmaxf(fmaxf(p0[i], p0[i + 8]), fmaxf(p1[i], p1[i + 8]));
        float mx = fmaxf(fmaxf(fmaxf(tm[0], tm[1]), fmaxf(tm[2], tm[3])),
                         fmaxf(fmaxf(tm[4], tm[5]), fmaxf(tm[6], tm[7])));
        mx = fmaxf(mx, __shfl_xor(mx, 32, 64));

        // defer-max: only rescale when the max moved by > 8 (P <= 2^8 ok)
        if (!__all(mx - mrow <= 8.0f)) {
            float mnew = fmaxf(mrow, mx);
            float sclf = EXP2(mrow - mnew);   // factor for q-row = l31
            lrow *= sclf;
            #pragma unroll
            for (int r = 0; r < 16; ++r) {    // oc[r] is q-row crow(r,hi)
                int src = (r & 3) + 8 * (r >> 2) + 4 * hi;
                float sf = __shfl(sclf, src, 64);
                oc0[r] *= sf;
                oc1[r] *= sf;
            }
            mrow = mnew;
        }

        // exp in place (base-2 domain)
        #pragma unroll
        for (int i = 0; i < 16; ++i) { p0[i] = EXP2(p0[i] - mrow); p1[i] = EXP2(p1[i] - mrow); }

        // in-lane sum + cross-half (l state is per q-row = l31)
        float s8[8];
        #pragma unroll
        for (int i = 0; i < 8; ++i)
            s8[i] = (p0[i] + p0[i + 8]) + (p1[i] + p1[i + 8]);
        float ts = ((s8[0] + s8[1]) + (s8[2] + s8[3])) + ((s8[4] + s8[5]) + (s8[6] + s8[7]));
        ts += __shfl_xor(ts, 32, 64);
        lrow += ts;

        // P -> A-fragments: cvt_pk pairs + v_permlane32_swap cross-half exchange
        s16x8 pa[4];
        #pragma unroll
        for (int g = 0; g < 4; ++g) {
            const f32x16 pv = (g < 2) ? p0 : p1;
            const int o = (g & 1) * 8;
            unsigned a0 = cvtpk(pv[o + 0], pv[o + 1]);
            unsigned a1 = cvtpk(pv[o + 2], pv[o + 3]);
            unsigned b0 = cvtpk(pv[o + 4], pv[o + 5]);
            unsigned b1 = cvtpk(pv[o + 6], pv[o + 7]);
            asm("v_permlane32_swap_b32 %0, %1" : "+v"(a0), "+v"(b0));
            asm("v_permlane32_swap_b32 %0, %1" : "+v"(a1), "+v"(b1));
            u32x4 t4 = {a0, a1, b0, b1};
            pa[g] = __builtin_bit_cast(s16x8, t4);
        }

        // O += P V : B-frag from Vs[d][k] (this wave's col half = byte par*128)
        __builtin_amdgcn_s_setprio(1);
        #pragma unroll
        for (int s = 0; s < 4; ++s) {
            int cbyte = par * 128 + s * 32 + hi * 16;
            int d0 = l31, d1 = 32 + l31;
            s16x8 vb0 = *(const s16x8*)(Vb + d0 * 256 + (cbyte ^ ((d0 & 15) << 4)));
            s16x8 vb1 = *(const s16x8*)(Vb + d1 * 256 + (cbyte ^ ((d1 & 15) << 4)));
            oc0 = __builtin_amdgcn_mfma_f32_32x32x16_bf16(pa[s], vb0, oc0, 0, 0, 0);
            oc1 = __builtin_amdgcn_mfma_f32_32x32x16_bf16(pa[s], vb1, oc1, 0, 0, 0);
        }
        __builtin_amdgcn_s_setprio(0);
    }

    // ---- cross-parity merge via LDS (exact flash combine) ----
    __syncthreads();
    float* Os = (float*)(void*)lds + qhf * 2048;   // [32 q][64 d] per q-half (16KB)
    float* ms = (float*)(void*)(lds + 16384);      // [64] m1 per (qhf,row)
    float* ls = ms + 64;                           // [64] l1
    if (par == 1) {
        if (hi == 0) { ms[qhf * 32 + l31] = mrow; ls[qhf * 32 + l31] = lrow; }
        #pragma unroll
        for (int r = 0; r < 16; ++r) {
            int rl = (r & 3) + 8 * (r >> 2) + 4 * hi;
            Os[rl * 64 + l31]      = oc0[r];
            Os[rl * 64 + 32 + l31] = oc1[r];
        }
    }
    __syncthreads();
    if (par == 0) {
        float m1 = ms[qhf * 32 + l31], l1 = ls[qhf * 32 + l31];
        float M  = fmaxf(mrow, m1);
        float wa = EXP2(mrow - M);
        float wb = EXP2(m1 - M);       // = 0 when parity-1 never saw valid cols
        float inv = 1.0f / (lrow * wa + l1 * wb);
        const int b = bh >> 4, h = bh & 15;
        #pragma unroll
        for (int r = 0; r < 16; ++r) {
            int rl = (r & 3) + 8 * (r >> 2) + 4 * hi;
            float ar = __shfl(wa, rl, 64);
            float br = __shfl(wb, rl, 64);
            float ir = __shfl(inv, rl, 64);
            size_t base = ((size_t)(b * SEQ + qb + qhf * 32 + rl) << 10) + h * 64;
            attnout[base + l31]      = f2b((oc0[r] * ar + Os[rl * 64 + l31]      * br) * ir);
            attnout[base + 32 + l31] = f2b((oc1[r] * ar + Os[rl * 64 + 32 + l31] * br) * ir);
        }
    }
}

// ---------- launch ----------
extern "C" void kernel_launch(void* const* d_in, const int* in_sizes, int n_in,
                              void* d_out, int out_size, void* d_ws, size_t ws_size,
                              hipStream_t stream) {
    const float* query = (const float*)d_in[0];
    const float* key   = (const float*)d_in[1];
    const float* value = (const float*)d_in[2];
    // d_in[3] = mask: causal, recomputed analytically
    const float* wq = (const float*)d_in[4];
    const float* bq = (const float*)d_in[5];
    const float* wk = (const float*)d_in[6];
    const float* bk = (const float*)d_in[7];
    const float* wv = (const float*)d_in[8];
    const float* bv = (const float*)d_in[9];
    const float* wo = (const float*)d_in[10];
    const float* bo = (const float*)d_in[11];
    float* out = (float*)d_out;

    char* ws = (char*)d_ws;
    unsigned short* xb  = (unsigned short*)ws;                 // [3][4096][1024] bf16; slot 0 reused as attn-out
    unsigned short* wt  = (unsigned short*)(ws + 25165824);    // [4][1024][1024] bf16 (wT: q,k,v,o)
    unsigned short* qhp = (unsigned short*)(ws + 33554432);    // [2][16][2048][64] bf16 (scaled)
    unsigned short* khp = (unsigned short*)(ws + 41943040);    // [2][16][2048][64] bf16
    unsigned short* vTp = (unsigned short*)(ws + 50331648);    // [2][16][64][2048] bf16
    // total ws use: 58,720,256 B

    cvt3_kernel<<<dim3(4096, 3), 256, 0, stream>>>(query, key, value, xb);
    wtrans_kernel<<<dim3(32, 32, 4), dim3(32, 8), 0, stream>>>(wq, wk, wv, wo, wt);
    gemm_kernel<128><<<dim3(32, 8, 3), 256, 0, stream>>>(0, xb, wt, bq, bk, bv, bo, qhp, khp, vTp, nullptr);
    attn_kernel<<<dim3(1024), 256, 0, stream>>>(qhp, khp, vTp, xb);
    gemm_kernel<64><<<dim3(64, 8, 1), 256, 0, stream>>>(3, xb, wt, bq, bk, bv, bo, qhp, khp, vTp, out);
}

// Round 12
// 100.656 us; speedup vs baseline: 1.8305x; 1.1008x over previous
//
#include <hip/hip_runtime.h>
#include <hip/hip_bf16.h>
#include <stdint.h>
#include <math.h>

typedef float f32x4  __attribute__((ext_vector_type(4)));
typedef float f32x16 __attribute__((ext_vector_type(16)));
typedef short s16x8  __attribute__((ext_vector_type(8)));
typedef unsigned u32x4 __attribute__((ext_vector_type(4)));

#define SEQ     2048
#define DMODEL  1024
#define MROWS   4096   // B*S
#define NHEAD   16

// ---------- helpers ----------
__device__ __forceinline__ unsigned short f2b(float x) {
    union { float f; unsigned u; } un; un.f = x;
    unsigned r = un.u + 0x7FFFu + ((un.u >> 16) & 1u);   // RNE to bf16
    return (unsigned short)(r >> 16);
}

__device__ __forceinline__ unsigned cvtpk(float lo, float hi_) {
    unsigned r;
    asm("v_cvt_pk_bf16_f32 %0, %1, %2" : "=v"(r) : "v"(lo), "v"(hi_));
    return r;
}

// raw v_exp_f32 (2^x) — avoids the OCML exp2f routine expansion
#define EXP2(x) __builtin_amdgcn_exp2f(x)

// async global->LDS, 16B per lane; LDS dest must be wave-uniform base (+lane*16 by HW)
__device__ __forceinline__ void g2l16(const void* g, void* l) {
    __builtin_amdgcn_global_load_lds(
        (const __attribute__((address_space(1))) unsigned int*)g,
        (__attribute__((address_space(3))) unsigned int*)l,
        16, 0, 0);
}

// ---------- kernel 1: f32 -> bf16 for query/key/value ----------
__global__ __launch_bounds__(256) void cvt3_kernel(
    const float* __restrict__ q, const float* __restrict__ k, const float* __restrict__ v,
    unsigned short* __restrict__ out)
{
    const float* in = blockIdx.y == 0 ? q : (blockIdx.y == 1 ? k : v);
    size_t i = ((size_t)blockIdx.x * 256 + threadIdx.x) * 4;
    float4 val = *(const float4*)(in + i);
    ushort4 o;
    o.x = f2b(val.x); o.y = f2b(val.y); o.z = f2b(val.z); o.w = f2b(val.w);
    *(ushort4*)(out + (size_t)blockIdx.y * ((size_t)MROWS * DMODEL) + i) = o;
}

// ---------- kernel 2: weight transpose + convert: wT[n][k] = bf16(w[k][n]) ----------
__global__ __launch_bounds__(256) void wtrans_kernel(
    const float* __restrict__ w0, const float* __restrict__ w1,
    const float* __restrict__ w2, const float* __restrict__ w3,
    unsigned short* __restrict__ wt)
{
    const int z = blockIdx.z;
    const float* w = z == 0 ? w0 : z == 1 ? w1 : z == 2 ? w2 : w3;
    __shared__ float t[32][33];
    const int bx = blockIdx.x * 32;   // n base
    const int by = blockIdx.y * 32;   // k base
    const int tx = threadIdx.x, ty = threadIdx.y;   // (32, 8)
    #pragma unroll
    for (int i = 0; i < 4; ++i)
        t[ty + i*8][tx] = w[(size_t)(by + ty + i*8) * DMODEL + bx + tx];  // t[krel][nrel]
    __syncthreads();
    unsigned short* o = wt + (size_t)z * ((size_t)DMODEL * DMODEL);
    #pragma unroll
    for (int i = 0; i < 4; ++i) {
        int nrel = ty + i*8, krel = tx;
        o[(size_t)(bx + nrel) * DMODEL + by + krel] = f2b(t[krel][nrel]);
    }
}

// ---------- kernel 3/5: bf16 MFMA GEMM, C = A[M,K] * Bt[N,K]^T + bias ----------
template<int TM>
__global__ __launch_bounds__(256, (TM == 128 ? 3 : 2)) void gemm_kernel(
    int mode_base,
    const unsigned short* __restrict__ xbase,
    const unsigned short* __restrict__ wtbase,
    const float* __restrict__ b0, const float* __restrict__ b1,
    const float* __restrict__ b2, const float* __restrict__ b3,
    unsigned short* __restrict__ qh, unsigned short* __restrict__ kh,
    unsigned short* __restrict__ vT, float* __restrict__ outF)
{
    constexpr int WM = TM / 2;      // wave rows
    constexpr int MT = WM / 16;     // m-tiles per wave
    const int mode = mode_base + blockIdx.z;
    const unsigned short* Ap = xbase + (size_t)(mode < 3 ? mode : 0) * ((size_t)MROWS * DMODEL);
    const unsigned short* Bt = wtbase + (size_t)mode * ((size_t)DMODEL * DMODEL);
    const float* bias = mode == 0 ? b0 : mode == 1 ? b1 : mode == 2 ? b2 : b3;

    __shared__ unsigned short As[TM * 64];
    __shared__ unsigned short Bs[128 * 64];

    const int tid = threadIdx.x;
    const int lane = tid & 63, wid = tid >> 6;
    const int ll = lane & 15, lg = lane >> 4;
    const int mb = blockIdx.x * TM, nb = blockIdx.y * 128;
    const int wr = wid >> 1, wc = wid & 1;

    f32x4 acc[MT][4] = {};

    for (int kb = 0; kb < DMODEL; kb += 64) {
        __syncthreads();
        #pragma unroll
        for (int is = 0; is < TM / 32; ++is) {     // stage A tile (TM x 64 bf16), swizzled source
            int ci = is * 256 + tid;
            int r = ci >> 3;
            int cbs = ((ci & 7) * 16) ^ ((r & 7) << 4);
            g2l16((const char*)Ap + ((size_t)(mb + r) * DMODEL + kb) * 2 + cbs,
                  (char*)As + (is * 256 + wid * 64) * 16);
        }
        #pragma unroll
        for (int is = 0; is < 4; ++is) {           // stage Bt tile (128 x 64 bf16)
            int ci = is * 256 + tid;
            int r = ci >> 3;
            int cbs = ((ci & 7) * 16) ^ ((r & 7) << 4);
            g2l16((const char*)Bt + ((size_t)(nb + r) * DMODEL + kb) * 2 + cbs,
                  (char*)Bs + (is * 256 + wid * 64) * 16);
        }
        __syncthreads();
        #pragma unroll
        for (int kk = 0; kk < 2; ++kk) {
            s16x8 af[MT], bfr[4];
            #pragma unroll
            for (int m = 0; m < MT; ++m) {
                int row = wr * WM + m * 16 + ll;
                int cbyte = (kk * 64 + lg * 16) ^ ((row & 7) << 4);
                af[m] = *(const s16x8*)((const char*)As + row * 128 + cbyte);
            }
            #pragma unroll
            for (int n = 0; n < 4; ++n) {
                int row = wc * 64 + n * 16 + ll;
                int cbyte = (kk * 64 + lg * 16) ^ ((row & 7) << 4);
                bfr[n] = *(const s16x8*)((const char*)Bs + row * 128 + cbyte);
            }
            #pragma unroll
            for (int m = 0; m < MT; ++m)
                #pragma unroll
                for (int n = 0; n < 4; ++n)
                    acc[m][n] = __builtin_amdgcn_mfma_f32_16x16x32_bf16(af[m], bfr[n], acc[m][n], 0, 0, 0);
        }
    }

    // epilogue: C/D layout col = lane&15, row = (lane>>4)*4 + r   [m89-verified]
    #pragma unroll
    for (int m = 0; m < MT; ++m) {
        int grow0 = mb + wr * WM + m * 16 + lg * 4;
        #pragma unroll
        for (int n = 0; n < 4; ++n) {
            int col = nb + wc * 64 + n * 16 + ll;
            float bc = bias[col];
            f32x4 v = acc[m][n];
            if (mode == 3) {
                #pragma unroll
                for (int r = 0; r < 4; ++r)
                    outF[(size_t)(grow0 + r) * DMODEL + col] = v[r] + bc;
            } else if (mode == 2) {
                int b = grow0 >> 11, s0 = grow0 & 2047;
                int h = col >> 6, d = col & 63;
                ushort4 pk;
                pk.x = f2b(v[0] + bc); pk.y = f2b(v[1] + bc);
                pk.z = f2b(v[2] + bc); pk.w = f2b(v[3] + bc);
                *(ushort4*)(vT + ((size_t)((b * NHEAD + h) * 64 + d) << 11) + s0) = pk;
            } else {
                unsigned short* dst = (mode == 0) ? qh : kh;
                // fold 1/sqrt(depth) * log2(e) into Q so softmax can use exp2
                float scl = (mode == 0) ? 0.125f * 1.44269504089f : 1.0f;
                int b = grow0 >> 11, s0 = grow0 & 2047;
                int h = col >> 6, d = col & 63;
                #pragma unroll
                for (int r = 0; r < 4; ++r)
                    dst[((size_t)(b * NHEAD + h) * SEQ + s0 + r) * 64 + d] = f2b((v[r] + bc) * scl);
            }
        }
    }
}

// ---------- kernel 4: causal flash attention, 4-wave k-split + async-STAGE ----------
// grid 1024 x 256thr, (bh = bid&31, j = 31 - bid/32), 64 q-rows, 128-col
// super-steps; wave = (qhalf, parity). T14 async-STAGE: next tile's global
// loads are issued into 32 VGPRs right after the LDS write, so L2 latency
// hides under the current step's full compute; LDS stays single-buffered
// (32KB). launch_bounds(256,3): unified VGPR+AGPR budget ~170 — no spill
// (R9 lesson: a 102 cap spilled the f32x16 accumulators).
__global__ __launch_bounds__(256, 3) void attn_kernel(
    const unsigned short* __restrict__ qh, const unsigned short* __restrict__ kh,
    const unsigned short* __restrict__ vT, unsigned short* __restrict__ attnout)
{
    const int bid = blockIdx.x;
    const int bh = bid & 31;
    const int j  = 31 - (bid >> 5);     // heavy-first (LPT)
    const int qb = j * 64;
    const int nss = (j >> 1) + 1;       // super-steps of 128 cols

    const unsigned short* Q = qh + (size_t)bh * (SEQ * 64);
    const unsigned short* K = kh + (size_t)bh * (SEQ * 64);
    const unsigned short* V = vT + (size_t)bh * (64 * SEQ);   // [64 d][2048 s]

    __shared__ char lds[32768];
    char* Kb = lds;            // K super-tile [128 k][64 d], 128B rows, swz (k&7)<<4
    char* Vb = lds + 16384;    // V super-tile [64 d][128 k], 256B rows, swz (d&15)<<4

    const int tid = threadIdx.x, lane = tid & 63, wid = tid >> 6;
    const int l31 = lane & 31, hi = lane >> 5;
    const int qhf = wid & 1;            // q-half
    const int par = wid >> 1;           // k-parity (col half)
    const int qrow = qb + qhf * 32 + l31;

    // Q B-fragments: lane holds Q[q=qrow][d = 16u + 8*hi + jj]  (pre-scaled log2e/8)
    s16x8 aq[4];
    {
        const unsigned short* qp = Q + (size_t)qrow * 64 + hi * 8;
        #pragma unroll
        for (int u = 0; u < 4; ++u)
            aq[u] = *(const s16x8*)(qp + u * 16);
    }

    f32x16 oc0 = {}, oc1 = {};     // O[q=crow(r,hi)][d]: d-halves 0..31 / 32..63
    float mrow = -1e30f, lrow = 0.f;

    // T14 register staging: 8 x 16B per thread (K tile slots 0..3, V 4..7).
    // Source addresses pre-swizzled (identical math to the g2l16 version);
    // LDS destination linear: slot (it*256+tid)*16 == lds + it*4096 + tid*16.
    u32x4 stg[8];
    auto issue = [&](int kb) {
        #pragma unroll
        for (int it = 0; it < 4; ++it) {          // K: 128 rows x 128B
            int ci = it * 256 + tid;
            int r = ci >> 3;
            int sb = ((ci & 7) * 16) ^ ((r & 7) << 4);
            stg[it] = *(const u32x4*)((const char*)K + ((size_t)(kb + r) * 64) * 2 + sb);
        }
        #pragma unroll
        for (int it = 0; it < 4; ++it) {          // V: 64 rows x 256B
            int ci = it * 256 + tid;
            int d = ci >> 4;
            int sb = ((ci & 15) * 16) ^ ((d & 15) << 4);
            stg[4 + it] = *(const u32x4*)((const char*)V + (size_t)d * (SEQ * 2) + (size_t)kb * 2 + sb);
        }
    };

    issue(0);

    for (int ss = 0; ss < nss; ++ss) {
        const int kb = ss * 128;
        __syncthreads();                // all waves done reading previous tile
        #pragma unroll
        for (int it = 0; it < 8; ++it)  // regs -> LDS (compiler waits vmcnt here)
            *(u32x4*)(lds + it * 4096 + tid * 16) = stg[it];
        if (ss + 1 < nss) issue(kb + 128);   // in flight across this step's compute
        __syncthreads();                // tile visible

        // S^T = K . Q^T on this wave's 64-col half: rows par*64 + [0,64)
        const int rb = par * 64;
        f32x16 p0 = {}, p1 = {};
        __builtin_amdgcn_s_setprio(1);
        #pragma unroll
        for (int u = 0; u < 4; ++u) {
            int r0 = rb + l31, r1 = rb + 32 + l31;
            s16x8 k0 = *(const s16x8*)(Kb + r0 * 128 + (((u * 32 + hi * 16)) ^ ((r0 & 7) << 4)));
            s16x8 k1 = *(const s16x8*)(Kb + r1 * 128 + (((u * 32 + hi * 16)) ^ ((r1 & 7) << 4)));
            p0 = __builtin_amdgcn_mfma_f32_32x32x16_bf16(k0, aq[u], p0, 0, 0, 0);
            p1 = __builtin_amdgcn_mfma_f32_32x32x16_bf16(k1, aq[u], p1, 0, 0, 0);
        }
        __builtin_amdgcn_s_setprio(0);

        if (ss == nss - 1) {           // diagonal super-step: mask k > q
            const int pabs = kb + rb;
            #pragma unroll
            for (int r = 0; r < 16; ++r) {
                int rl = (r & 3) + 8 * (r >> 2) + 4 * hi;
                if (pabs + rl > qrow)      p0[r] = -1e30f;
                if (pabs + 32 + rl > qrow) p1[r] = -1e30f;
            }
        }

        // in-lane row max over 32 values, then cross-half
        float tm[8];
        #pragma unroll
        for (int i = 0; i < 8; ++i)
            tm[i] = fmaxf(fmaxf(p0[i], p0[i + 8]), fmaxf(p1[i], p1[i + 8]));
        float mx = fmaxf(fmaxf(fmaxf(tm[0], tm[1]), fmaxf(tm[2], tm[3])),
                         fmaxf(fmaxf(tm[4], tm[5]), fmaxf(tm[6], tm[7])));
        mx = fmaxf(mx, __shfl_xor(mx, 32, 64));

        // defer-max: only rescale when the max moved by > 8 (P <= 2^8 ok)
        if (!__all(mx - mrow <= 8.0f)) {
            float mnew = fmaxf(mrow, mx);
            float sclf = EXP2(mrow - mnew);   // factor for q-row = l31
            lrow *= sclf;
            #pragma unroll
            for (int r = 0; r < 16; ++r) {    // oc[r] is q-row crow(r,hi)
                int src = (r & 3) + 8 * (r >> 2) + 4 * hi;
                float sf = __shfl(sclf, src, 64);
                oc0[r] *= sf;
                oc1[r] *= sf;
            }
            mrow = mnew;
        }

        // exp in place (base-2 domain)
        #pragma unroll
        for (int i = 0; i < 16; ++i) { p0[i] = EXP2(p0[i] - mrow); p1[i] = EXP2(p1[i] - mrow); }

        // in-lane sum + cross-half (l state is per q-row = l31)
        float s8[8];
        #pragma unroll
        for (int i = 0; i < 8; ++i)
            s8[i] = (p0[i] + p0[i + 8]) + (p1[i] + p1[i + 8]);
        float ts = ((s8[0] + s8[1]) + (s8[2] + s8[3])) + ((s8[4] + s8[5]) + (s8[6] + s8[7]));
        ts += __shfl_xor(ts, 32, 64);
        lrow += ts;

        // P -> A-fragments: cvt_pk pairs + v_permlane32_swap cross-half exchange
        s16x8 pa[4];
        #pragma unroll
        for (int g = 0; g < 4; ++g) {
            const f32x16 pv = (g < 2) ? p0 : p1;
            const int o = (g & 1) * 8;
            unsigned a0 = cvtpk(pv[o + 0], pv[o + 1]);
            unsigned a1 = cvtpk(pv[o + 2], pv[o + 3]);
            unsigned b0 = cvtpk(pv[o + 4], pv[o + 5]);
            unsigned b1 = cvtpk(pv[o + 6], pv[o + 7]);
            asm("v_permlane32_swap_b32 %0, %1" : "+v"(a0), "+v"(b0));
            asm("v_permlane32_swap_b32 %0, %1" : "+v"(a1), "+v"(b1));
            u32x4 t4 = {a0, a1, b0, b1};
            pa[g] = __builtin_bit_cast(s16x8, t4);
        }

        // O += P V : B-frag from Vs[d][k] (this wave's col half = byte par*128)
        __builtin_amdgcn_s_setprio(1);
        #pragma unroll
        for (int s = 0; s < 4; ++s) {
            int cbyte = par * 128 + s * 32 + hi * 16;
            int d0 = l31, d1 = 32 + l31;
            s16x8 vb0 = *(const s16x8*)(Vb + d0 * 256 + (cbyte ^ ((d0 & 15) << 4)));
            s16x8 vb1 = *(const s16x8*)(Vb + d1 * 256 + (cbyte ^ ((d1 & 15) << 4)));
            oc0 = __builtin_amdgcn_mfma_f32_32x32x16_bf16(pa[s], vb0, oc0, 0, 0, 0);
            oc1 = __builtin_amdgcn_mfma_f32_32x32x16_bf16(pa[s], vb1, oc1, 0, 0, 0);
        }
        __builtin_amdgcn_s_setprio(0);
    }

    // ---- cross-parity merge via LDS (exact flash combine) ----
    __syncthreads();
    float* Os = (float*)(void*)lds + qhf * 2048;   // [32 q][64 d] per q-half (16KB)
    float* ms = (float*)(void*)(lds + 16384);      // [64] m1 per (qhf,row)
    float* ls = ms + 64;                           // [64] l1
    if (par == 1) {
        if (hi == 0) { ms[qhf * 32 + l31] = mrow; ls[qhf * 32 + l31] = lrow; }
        #pragma unroll
        for (int r = 0; r < 16; ++r) {
            int rl = (r & 3) + 8 * (r >> 2) + 4 * hi;
            Os[rl * 64 + l31]      = oc0[r];
            Os[rl * 64 + 32 + l31] = oc1[r];
        }
    }
    __syncthreads();
    if (par == 0) {
        float m1 = ms[qhf * 32 + l31], l1 = ls[qhf * 32 + l31];
        float M  = fmaxf(mrow, m1);
        float wa = EXP2(mrow - M);
        float wb = EXP2(m1 - M);       // = 0 when parity-1 never saw valid cols
        float inv = 1.0f / (lrow * wa + l1 * wb);
        const int b = bh >> 4, h = bh & 15;
        #pragma unroll
        for (int r = 0; r < 16; ++r) {
            int rl = (r & 3) + 8 * (r >> 2) + 4 * hi;
            float ar = __shfl(wa, rl, 64);
            float br = __shfl(wb, rl, 64);
            float ir = __shfl(inv, rl, 64);
            size_t base = ((size_t)(b * SEQ + qb + qhf * 32 + rl) << 10) + h * 64;
            attnout[base + l31]      = f2b((oc0[r] * ar + Os[rl * 64 + l31]      * br) * ir);
            attnout[base + 32 + l31] = f2b((oc1[r] * ar + Os[rl * 64 + 32 + l31] * br) * ir);
        }
    }
}

// ---------- launch ----------
extern "C" void kernel_launch(void* const* d_in, const int* in_sizes, int n_in,
                              void* d_out, int out_size, void* d_ws, size_t ws_size,
                              hipStream_t stream) {
    const float* query = (const float*)d_in[0];
    const float* key   = (const float*)d_in[1];
    const float* value = (const float*)d_in[2];
    // d_in[3] = mask: causal, recomputed analytically
    const float* wq = (const float*)d_in[4];
    const float* bq = (const float*)d_in[5];
    const float* wk = (const float*)d_in[6];
    const float* bk = (const float*)d_in[7];
    const float* wv = (const float*)d_in[8];
    const float* bv = (const float*)d_in[9];
    const float* wo = (const float*)d_in[10];
    const float* bo = (const float*)d_in[11];
    float* out = (float*)d_out;

    char* ws = (char*)d_ws;
    unsigned short* xb  = (unsigned short*)ws;                 // [3][4096][1024] bf16; slot 0 reused as attn-out
    unsigned short* wt  = (unsigned short*)(ws + 25165824);    // [4][1024][1024] bf16 (wT: q,k,v,o)
    unsigned short* qhp = (unsigned short*)(ws + 33554432);    // [2][16][2048][64] bf16 (scaled)
    unsigned short* khp = (unsigned short*)(ws + 41943040);    // [2][16][2048][64] bf16
    unsigned short* vTp = (unsigned short*)(ws + 50331648);    // [2][16][64][2048] bf16
    // total ws use: 58,720,256 B

    cvt3_kernel<<<dim3(4096, 3), 256, 0, stream>>>(query, key, value, xb);
    wtrans_kernel<<<dim3(32, 32, 4), dim3(32, 8), 0, stream>>>(wq, wk, wv, wo, wt);
    gemm_kernel<128><<<dim3(32, 8, 3), 256, 0, stream>>>(0, xb, wt, bq, bk, bv, bo, qhp, khp, vTp, nullptr);
    attn_kernel<<<dim3(1024), 256, 0, stream>>>(qhp, khp, vTp, xb);
    gemm_kernel<64><<<dim3(64, 8, 1), 256, 0, stream>>>(3, xb, wt, bq, bk, bv, bo, qhp, khp, vTp, out);
}

// Round 13
// 97.996 us; speedup vs baseline: 1.8802x; 1.0271x over previous
//
#include <hip/hip_runtime.h>
#include <hip/hip_bf16.h>
#include <stdint.h>
#include <math.h>

typedef float f32x4  __attribute__((ext_vector_type(4)));
typedef float f32x16 __attribute__((ext_vector_type(16)));
typedef short s16x8  __attribute__((ext_vector_type(8)));
typedef unsigned u32x4 __attribute__((ext_vector_type(4)));

#define SEQ     2048
#define DMODEL  1024
#define MROWS   4096   // B*S
#define NHEAD   16

// ---------- helpers ----------
__device__ __forceinline__ unsigned short f2b(float x) {
    union { float f; unsigned u; } un; un.f = x;
    unsigned r = un.u + 0x7FFFu + ((un.u >> 16) & 1u);   // RNE to bf16
    return (unsigned short)(r >> 16);
}

__device__ __forceinline__ unsigned cvtpk(float lo, float hi_) {
    unsigned r;
    asm("v_cvt_pk_bf16_f32 %0, %1, %2" : "=v"(r) : "v"(lo), "v"(hi_));
    return r;
}

// raw v_exp_f32 (2^x) — avoids the OCML exp2f routine expansion
#define EXP2(x) __builtin_amdgcn_exp2f(x)

// async global->LDS, 16B per lane; LDS dest must be wave-uniform base (+lane*16 by HW)
__device__ __forceinline__ void g2l16(const void* g, void* l) {
    __builtin_amdgcn_global_load_lds(
        (const __attribute__((address_space(1))) unsigned int*)g,
        (__attribute__((address_space(3))) unsigned int*)l,
        16, 0, 0);
}

// ---------- kernel 2: weight transpose + convert: wT[n][k] = bf16(w[k][n]) ----------
__global__ __launch_bounds__(256) void wtrans_kernel(
    const float* __restrict__ w0, const float* __restrict__ w1,
    const float* __restrict__ w2, const float* __restrict__ w3,
    unsigned short* __restrict__ wt)
{
    const int z = blockIdx.z;
    const float* w = z == 0 ? w0 : z == 1 ? w1 : z == 2 ? w2 : w3;
    __shared__ float t[32][33];
    const int bx = blockIdx.x * 32;   // n base
    const int by = blockIdx.y * 32;   // k base
    const int tx = threadIdx.x, ty = threadIdx.y;   // (32, 8)
    #pragma unroll
    for (int i = 0; i < 4; ++i)
        t[ty + i*8][tx] = w[(size_t)(by + ty + i*8) * DMODEL + bx + tx];  // t[krel][nrel]
    __syncthreads();
    unsigned short* o = wt + (size_t)z * ((size_t)DMODEL * DMODEL);
    #pragma unroll
    for (int i = 0; i < 4; ++i) {
        int nrel = ty + i*8, krel = tx;
        o[(size_t)(bx + nrel) * DMODEL + by + krel] = f2b(t[krel][nrel]);
    }
}

// ---------- kernel 3: fused QKV GEMM, A = f32 input (inline cvt), T14 staging ----
// C = bf16(A_f32)[M,K] * Bt[N,K]^T + bias. 128x128 tile, BK=64, 4 waves.
// A: reg-staged (8 x float4/thread) with cvt_pk at LDS-write; next tile's loads
// issued right after barrier (b) so HBM latency hides under the 32-MFMA compute.
// B: global_load_lds (weights are L2-hot, ~2MB/mode). Same swizzle convention
// as before: pre-swizzled SOURCE -> linear LDS slot -> swizzled read.
// mode 0: Q -> qh[b][h][s][64] scaled by log2e/8; mode 1: K -> kh; mode 2: V -> vT.
__global__ __launch_bounds__(256, 3) void gemm_qkv_kernel(
    const float* __restrict__ qf, const float* __restrict__ kf, const float* __restrict__ vf,
    const unsigned short* __restrict__ wtbase,
    const float* __restrict__ b0, const float* __restrict__ b1, const float* __restrict__ b2,
    unsigned short* __restrict__ qh, unsigned short* __restrict__ kh,
    unsigned short* __restrict__ vT)
{
    const int mode = blockIdx.z;
    const float* Af = mode == 0 ? qf : mode == 1 ? kf : vf;
    const unsigned short* Bt = wtbase + (size_t)mode * ((size_t)DMODEL * DMODEL);
    const float* bias = mode == 0 ? b0 : mode == 1 ? b1 : b2;

    __shared__ unsigned short As[128 * 64];
    __shared__ unsigned short Bs[128 * 64];

    const int tid = threadIdx.x;
    const int lane = tid & 63, wid = tid >> 6;
    const int ll = lane & 15, lg = lane >> 4;
    const int mb = blockIdx.x * 128, nb = blockIdx.y * 128;
    const int wr = wid >> 1, wc = wid & 1;

    f32x4 acc[4][4] = {};
    f32x4 stgA[8];

    // issue A-tile loads (f32, pre-swizzled source addressing; 2 float4 / chunk)
    auto issueA = [&](int kb) {
        #pragma unroll
        for (int it = 0; it < 4; ++it) {
            int ci = it * 256 + tid;
            int r = ci >> 3;
            int cbs = ((ci & 7) * 16) ^ ((r & 7) << 4);      // bf16 byte off in 128B row
            const float* src = Af + (size_t)(mb + r) * DMODEL + kb + (cbs >> 1);
            stgA[2 * it]     = *(const f32x4*)src;
            stgA[2 * it + 1] = *(const f32x4*)(src + 4);
        }
    };

    issueA(0);

    for (int kb = 0; kb < DMODEL; kb += 64) {
        __syncthreads();                    // all waves done reading LDS
        #pragma unroll
        for (int it = 0; it < 4; ++it) {    // cvt + write A chunk to linear slot
            u32x4 w = { cvtpk(stgA[2*it][0],   stgA[2*it][1]),
                        cvtpk(stgA[2*it][2],   stgA[2*it][3]),
                        cvtpk(stgA[2*it+1][0], stgA[2*it+1][1]),
                        cvtpk(stgA[2*it+1][2], stgA[2*it+1][3]) };
            *(u32x4*)((char*)As + (it * 256 + tid) * 16) = w;
        }
        #pragma unroll
        for (int it = 0; it < 4; ++it) {    // stage B tile (bf16 weights, L2-hot)
            int ci = it * 256 + tid;
            int r = ci >> 3;
            int cbs = ((ci & 7) * 16) ^ ((r & 7) << 4);
            g2l16((const char*)Bt + ((size_t)(nb + r) * DMODEL + kb) * 2 + cbs,
                  (char*)Bs + (it * 256 + wid * 64) * 16);
        }
        __syncthreads();                    // B drained, A writes visible
        if (kb + 64 < DMODEL) issueA(kb + 64);   // T14: in flight across compute

        #pragma unroll
        for (int kk = 0; kk < 2; ++kk) {
            s16x8 af[4], bfr[4];
            #pragma unroll
            for (int m = 0; m < 4; ++m) {
                int row = wr * 64 + m * 16 + ll;
                int cbyte = (kk * 64 + lg * 16) ^ ((row & 7) << 4);
                af[m] = *(const s16x8*)((const char*)As + row * 128 + cbyte);
            }
            #pragma unroll
            for (int n = 0; n < 4; ++n) {
                int row = wc * 64 + n * 16 + ll;
                int cbyte = (kk * 64 + lg * 16) ^ ((row & 7) << 4);
                bfr[n] = *(const s16x8*)((const char*)Bs + row * 128 + cbyte);
            }
            #pragma unroll
            for (int m = 0; m < 4; ++m)
                #pragma unroll
                for (int n = 0; n < 4; ++n)
                    acc[m][n] = __builtin_amdgcn_mfma_f32_16x16x32_bf16(af[m], bfr[n], acc[m][n], 0, 0, 0);
        }
    }

    // epilogue (same mapping as before): col = lane&15, row = (lane>>4)*4 + r
    #pragma unroll
    for (int m = 0; m < 4; ++m) {
        int grow0 = mb + wr * 64 + m * 16 + lg * 4;
        #pragma unroll
        for (int n = 0; n < 4; ++n) {
            int col = nb + wc * 64 + n * 16 + ll;
            float bc = bias[col];
            f32x4 v = acc[m][n];
            if (mode == 2) {
                int b = grow0 >> 11, s0 = grow0 & 2047;
                int h = col >> 6, d = col & 63;
                ushort4 pk;
                pk.x = f2b(v[0] + bc); pk.y = f2b(v[1] + bc);
                pk.z = f2b(v[2] + bc); pk.w = f2b(v[3] + bc);
                *(ushort4*)(vT + ((size_t)((b * NHEAD + h) * 64 + d) << 11) + s0) = pk;
            } else {
                unsigned short* dst = (mode == 0) ? qh : kh;
                float scl = (mode == 0) ? 0.125f * 1.44269504089f : 1.0f;
                int b = grow0 >> 11, s0 = grow0 & 2047;
                int h = col >> 6, d = col & 63;
                #pragma unroll
                for (int r = 0; r < 4; ++r)
                    dst[((size_t)(b * NHEAD + h) * SEQ + s0 + r) * 64 + d] = f2b((v[r] + bc) * scl);
            }
        }
    }
}

// ---------- kernel 5: O-projection GEMM (bf16 A from ws), unchanged ----------
template<int TM>
__global__ __launch_bounds__(256, 2) void gemm_kernel(
    const unsigned short* __restrict__ Ap,
    const unsigned short* __restrict__ Bt,
    const float* __restrict__ bias,
    float* __restrict__ outF)
{
    constexpr int WM = TM / 2;      // wave rows
    constexpr int MT = WM / 16;     // m-tiles per wave

    __shared__ unsigned short As[TM * 64];
    __shared__ unsigned short Bs[128 * 64];

    const int tid = threadIdx.x;
    const int lane = tid & 63, wid = tid >> 6;
    const int ll = lane & 15, lg = lane >> 4;
    const int mb = blockIdx.x * TM, nb = blockIdx.y * 128;
    const int wr = wid >> 1, wc = wid & 1;

    f32x4 acc[MT][4] = {};

    for (int kb = 0; kb < DMODEL; kb += 64) {
        __syncthreads();
        #pragma unroll
        for (int is = 0; is < TM / 32; ++is) {     // stage A tile, swizzled source
            int ci = is * 256 + tid;
            int r = ci >> 3;
            int cbs = ((ci & 7) * 16) ^ ((r & 7) << 4);
            g2l16((const char*)Ap + ((size_t)(mb + r) * DMODEL + kb) * 2 + cbs,
                  (char*)As + (is * 256 + wid * 64) * 16);
        }
        #pragma unroll
        for (int is = 0; is < 4; ++is) {           // stage Bt tile
            int ci = is * 256 + tid;
            int r = ci >> 3;
            int cbs = ((ci & 7) * 16) ^ ((r & 7) << 4);
            g2l16((const char*)Bt + ((size_t)(nb + r) * DMODEL + kb) * 2 + cbs,
                  (char*)Bs + (is * 256 + wid * 64) * 16);
        }
        __syncthreads();
        #pragma unroll
        for (int kk = 0; kk < 2; ++kk) {
            s16x8 af[MT], bfr[4];
            #pragma unroll
            for (int m = 0; m < MT; ++m) {
                int row = wr * WM + m * 16 + ll;
                int cbyte = (kk * 64 + lg * 16) ^ ((row & 7) << 4);
                af[m] = *(const s16x8*)((const char*)As + row * 128 + cbyte);
            }
            #pragma unroll
            for (int n = 0; n < 4; ++n) {
                int row = wc * 64 + n * 16 + ll;
                int cbyte = (kk * 64 + lg * 16) ^ ((row & 7) << 4);
                bfr[n] = *(const s16x8*)((const char*)Bs + row * 128 + cbyte);
            }
            #pragma unroll
            for (int m = 0; m < MT; ++m)
                #pragma unroll
                for (int n = 0; n < 4; ++n)
                    acc[m][n] = __builtin_amdgcn_mfma_f32_16x16x32_bf16(af[m], bfr[n], acc[m][n], 0, 0, 0);
        }
    }

    #pragma unroll
    for (int m = 0; m < MT; ++m) {
        int grow0 = mb + wr * WM + m * 16 + lg * 4;
        #pragma unroll
        for (int n = 0; n < 4; ++n) {
            int col = nb + wc * 64 + n * 16 + ll;
            float bc = bias[col];
            f32x4 v = acc[m][n];
            #pragma unroll
            for (int r = 0; r < 4; ++r)
                outF[(size_t)(grow0 + r) * DMODEL + col] = v[r] + bc;
        }
    }
}

// ---------- kernel 4: causal flash attention, 4-wave k-split + async-STAGE ----------
// (unchanged from R12: 43 µs, passed)
__global__ __launch_bounds__(256, 3) void attn_kernel(
    const unsigned short* __restrict__ qh, const unsigned short* __restrict__ kh,
    const unsigned short* __restrict__ vT, unsigned short* __restrict__ attnout)
{
    const int bid = blockIdx.x;
    const int bh = bid & 31;
    const int j  = 31 - (bid >> 5);     // heavy-first (LPT)
    const int qb = j * 64;
    const int nss = (j >> 1) + 1;       // super-steps of 128 cols

    const unsigned short* Q = qh + (size_t)bh * (SEQ * 64);
    const unsigned short* K = kh + (size_t)bh * (SEQ * 64);
    const unsigned short* V = vT + (size_t)bh * (64 * SEQ);   // [64 d][2048 s]

    __shared__ char lds[32768];
    char* Kb = lds;            // K super-tile [128 k][64 d], 128B rows, swz (k&7)<<4
    char* Vb = lds + 16384;    // V super-tile [64 d][128 k], 256B rows, swz (d&15)<<4

    const int tid = threadIdx.x, lane = tid & 63, wid = tid >> 6;
    const int l31 = lane & 31, hi = lane >> 5;
    const int qhf = wid & 1;            // q-half
    const int par = wid >> 1;           // k-parity (col half)
    const int qrow = qb + qhf * 32 + l31;

    // Q B-fragments: lane holds Q[q=qrow][d = 16u + 8*hi + jj]  (pre-scaled log2e/8)
    s16x8 aq[4];
    {
        const unsigned short* qp = Q + (size_t)qrow * 64 + hi * 8;
        #pragma unroll
        for (int u = 0; u < 4; ++u)
            aq[u] = *(const s16x8*)(qp + u * 16);
    }

    f32x16 oc0 = {}, oc1 = {};     // O[q=crow(r,hi)][d]: d-halves 0..31 / 32..63
    float mrow = -1e30f, lrow = 0.f;

    u32x4 stg[8];
    auto issue = [&](int kb) {
        #pragma unroll
        for (int it = 0; it < 4; ++it) {          // K: 128 rows x 128B
            int ci = it * 256 + tid;
            int r = ci >> 3;
            int sb = ((ci & 7) * 16) ^ ((r & 7) << 4);
            stg[it] = *(const u32x4*)((const char*)K + ((size_t)(kb + r) * 64) * 2 + sb);
        }
        #pragma unroll
        for (int it = 0; it < 4; ++it) {          // V: 64 rows x 256B
            int ci = it * 256 + tid;
            int d = ci >> 4;
            int sb = ((ci & 15) * 16) ^ ((d & 15) << 4);
            stg[4 + it] = *(const u32x4*)((const char*)V + (size_t)d * (SEQ * 2) + (size_t)kb * 2 + sb);
        }
    };

    issue(0);

    for (int ss = 0; ss < nss; ++ss) {
        const int kb = ss * 128;
        __syncthreads();                // all waves done reading previous tile
        #pragma unroll
        for (int it = 0; it < 8; ++it)  // regs -> LDS (compiler waits vmcnt here)
            *(u32x4*)(lds + it * 4096 + tid * 16) = stg[it];
        if (ss + 1 < nss) issue(kb + 128);   // in flight across this step's compute
        __syncthreads();                // tile visible

        // S^T = K . Q^T on this wave's 64-col half: rows par*64 + [0,64)
        const int rb = par * 64;
        f32x16 p0 = {}, p1 = {};
        __builtin_amdgcn_s_setprio(1);
        #pragma unroll
        for (int u = 0; u < 4; ++u) {
            int r0 = rb + l31, r1 = rb + 32 + l31;
            s16x8 k0 = *(const s16x8*)(Kb + r0 * 128 + (((u * 32 + hi * 16)) ^ ((r0 & 7) << 4)));
            s16x8 k1 = *(const s16x8*)(Kb + r1 * 128 + (((u * 32 + hi * 16)) ^ ((r1 & 7) << 4)));
            p0 = __builtin_amdgcn_mfma_f32_32x32x16_bf16(k0, aq[u], p0, 0, 0, 0);
            p1 = __builtin_amdgcn_mfma_f32_32x32x16_bf16(k1, aq[u], p1, 0, 0, 0);
        }
        __builtin_amdgcn_s_setprio(0);

        if (ss == nss - 1) {           // diagonal super-step: mask k > q
            const int pabs = kb + rb;
            #pragma unroll
            for (int r = 0; r < 16; ++r) {
                int rl = (r & 3) + 8 * (r >> 2) + 4 * hi;
                if (pabs + rl > qrow)      p0[r] = -1e30f;
                if (pabs + 32 + rl > qrow) p1[r] = -1e30f;
            }
        }

        // in-lane row max over 32 values, then cross-half
        float tm[8];
        #pragma unroll
        for (int i = 0; i < 8; ++i)
            tm[i] = fmaxf(fmaxf(p0[i], p0[i + 8]), fmaxf(p1[i], p1[i + 8]));
        float mx = fmaxf(fmaxf(fmaxf(tm[0], tm[1]), fmaxf(tm[2], tm[3])),
                         fmaxf(fmaxf(tm[4], tm[5]), fmaxf(tm[6], tm[7])));
        mx = fmaxf(mx, __shfl_xor(mx, 32, 64));

        // defer-max: only rescale when the max moved by > 8 (P <= 2^8 ok)
        if (!__all(mx - mrow <= 8.0f)) {
            float mnew = fmaxf(mrow, mx);
            float sclf = EXP2(mrow - mnew);   // factor for q-row = l31
            lrow *= sclf;
            #pragma unroll
            for (int r = 0; r < 16; ++r) {    // oc[r] is q-row crow(r,hi)
                int src = (r & 3) + 8 * (r >> 2) + 4 * hi;
                float sf = __shfl(sclf, src, 64);
                oc0[r] *= sf;
                oc1[r] *= sf;
            }
            mrow = mnew;
        }

        // exp in place (base-2 domain)
        #pragma unroll
        for (int i = 0; i < 16; ++i) { p0[i] = EXP2(p0[i] - mrow); p1[i] = EXP2(p1[i] - mrow); }

        // in-lane sum + cross-half (l state is per q-row = l31)
        float s8[8];
        #pragma unroll
        for (int i = 0; i < 8; ++i)
            s8[i] = (p0[i] + p0[i + 8]) + (p1[i] + p1[i + 8]);
        float ts = ((s8[0] + s8[1]) + (s8[2] + s8[3])) + ((s8[4] + s8[5]) + (s8[6] + s8[7]));
        ts += __shfl_xor(ts, 32, 64);
        lrow += ts;

        // P -> A-fragments: cvt_pk pairs + v_permlane32_swap cross-half exchange
        s16x8 pa[4];
        #pragma unroll
        for (int g = 0; g < 4; ++g) {
            const f32x16 pv = (g < 2) ? p0 : p1;
            const int o = (g & 1) * 8;
            unsigned a0 = cvtpk(pv[o + 0], pv[o + 1]);
            unsigned a1 = cvtpk(pv[o + 2], pv[o + 3]);
            unsigned b0 = cvtpk(pv[o + 4], pv[o + 5]);
            unsigned b1 = cvtpk(pv[o + 6], pv[o + 7]);
            asm("v_permlane32_swap_b32 %0, %1" : "+v"(a0), "+v"(b0));
            asm("v_permlane32_swap_b32 %0, %1" : "+v"(a1), "+v"(b1));
            u32x4 t4 = {a0, a1, b0, b1};
            pa[g] = __builtin_bit_cast(s16x8, t4);
        }

        // O += P V : B-frag from Vs[d][k] (this wave's col half = byte par*128)
        __builtin_amdgcn_s_setprio(1);
        #pragma unroll
        for (int s = 0; s < 4; ++s) {
            int cbyte = par * 128 + s * 32 + hi * 16;
            int d0 = l31, d1 = 32 + l31;
            s16x8 vb0 = *(const s16x8*)(Vb + d0 * 256 + (cbyte ^ ((d0 & 15) << 4)));
            s16x8 vb1 = *(const s16x8*)(Vb + d1 * 256 + (cbyte ^ ((d1 & 15) << 4)));
            oc0 = __builtin_amdgcn_mfma_f32_32x32x16_bf16(pa[s], vb0, oc0, 0, 0, 0);
            oc1 = __builtin_amdgcn_mfma_f32_32x32x16_bf16(pa[s], vb1, oc1, 0, 0, 0);
        }
        __builtin_amdgcn_s_setprio(0);
    }

    // ---- cross-parity merge via LDS (exact flash combine) ----
    __syncthreads();
    float* Os = (float*)(void*)lds + qhf * 2048;   // [32 q][64 d] per q-half (16KB)
    float* ms = (float*)(void*)(lds + 16384);      // [64] m1 per (qhf,row)
    float* ls = ms + 64;                           // [64] l1
    if (par == 1) {
        if (hi == 0) { ms[qhf * 32 + l31] = mrow; ls[qhf * 32 + l31] = lrow; }
        #pragma unroll
        for (int r = 0; r < 16; ++r) {
            int rl = (r & 3) + 8 * (r >> 2) + 4 * hi;
            Os[rl * 64 + l31]      = oc0[r];
            Os[rl * 64 + 32 + l31] = oc1[r];
        }
    }
    __syncthreads();
    if (par == 0) {
        float m1 = ms[qhf * 32 + l31], l1 = ls[qhf * 32 + l31];
        float M  = fmaxf(mrow, m1);
        float wa = EXP2(mrow - M);
        float wb = EXP2(m1 - M);       // = 0 when parity-1 never saw valid cols
        float inv = 1.0f / (lrow * wa + l1 * wb);
        const int b = bh >> 4, h = bh & 15;
        #pragma unroll
        for (int r = 0; r < 16; ++r) {
            int rl = (r & 3) + 8 * (r >> 2) + 4 * hi;
            float ar = __shfl(wa, rl, 64);
            float br = __shfl(wb, rl, 64);
            float ir = __shfl(inv, rl, 64);
            size_t base = ((size_t)(b * SEQ + qb + qhf * 32 + rl) << 10) + h * 64;
            attnout[base + l31]      = f2b((oc0[r] * ar + Os[rl * 64 + l31]      * br) * ir);
            attnout[base + 32 + l31] = f2b((oc1[r] * ar + Os[rl * 64 + 32 + l31] * br) * ir);
        }
    }
}

// ---------- launch ----------
extern "C" void kernel_launch(void* const* d_in, const int* in_sizes, int n_in,
                              void* d_out, int out_size, void* d_ws, size_t ws_size,
                              hipStream_t stream) {
    const float* query = (const float*)d_in[0];
    const float* key   = (const float*)d_in[1];
    const float* value = (const float*)d_in[2];
    // d_in[3] = mask: causal, recomputed analytically
    const float* wq = (const float*)d_in[4];
    const float* bq = (const float*)d_in[5];
    const float* wk = (const float*)d_in[6];
    const float* bk = (const float*)d_in[7];
    const float* wv = (const float*)d_in[8];
    const float* bv = (const float*)d_in[9];
    const float* wo = (const float*)d_in[10];
    const float* bo = (const float*)d_in[11];
    float* out = (float*)d_out;

    char* ws = (char*)d_ws;
    unsigned short* xb  = (unsigned short*)ws;                 // [4096][1024] bf16 attn-out
    unsigned short* wt  = (unsigned short*)(ws + 25165824);    // [4][1024][1024] bf16 (wT: q,k,v,o)
    unsigned short* qhp = (unsigned short*)(ws + 33554432);    // [2][16][2048][64] bf16 (scaled)
    unsigned short* khp = (unsigned short*)(ws + 41943040);    // [2][16][2048][64] bf16
    unsigned short* vTp = (unsigned short*)(ws + 50331648);    // [2][16][64][2048] bf16
    // total ws use: 58,720,256 B

    wtrans_kernel<<<dim3(32, 32, 4), dim3(32, 8), 0, stream>>>(wq, wk, wv, wo, wt);
    gemm_qkv_kernel<<<dim3(32, 8, 3), 256, 0, stream>>>(query, key, value, wt,
                                                        bq, bk, bv, qhp, khp, vTp);
    attn_kernel<<<dim3(1024), 256, 0, stream>>>(qhp, khp, vTp, xb);
    gemm_kernel<64><<<dim3(64, 8), 256, 0, stream>>>(xb, wt + 3 * (size_t)(DMODEL * DMODEL), bo, out);
}

// Round 14
// 97.714 us; speedup vs baseline: 1.8856x; 1.0029x over previous
//
#include <hip/hip_runtime.h>
#include <hip/hip_bf16.h>
#include <stdint.h>
#include <math.h>

typedef float f32x4  __attribute__((ext_vector_type(4)));
typedef float f32x16 __attribute__((ext_vector_type(16)));
typedef short s16x8  __attribute__((ext_vector_type(8)));
typedef unsigned u32x4 __attribute__((ext_vector_type(4)));

#define SEQ     2048
#define DMODEL  1024
#define MROWS   4096   // B*S
#define NHEAD   16

// ---------- helpers ----------
__device__ __forceinline__ unsigned short f2b(float x) {
    union { float f; unsigned u; } un; un.f = x;
    unsigned r = un.u + 0x7FFFu + ((un.u >> 16) & 1u);   // RNE to bf16
    return (unsigned short)(r >> 16);
}

__device__ __forceinline__ unsigned cvtpk(float lo, float hi_) {
    unsigned r;
    asm("v_cvt_pk_bf16_f32 %0, %1, %2" : "=v"(r) : "v"(lo), "v"(hi_));
    return r;
}

// raw v_exp_f32 (2^x) — avoids the OCML exp2f routine expansion
#define EXP2(x) __builtin_amdgcn_exp2f(x)

// async global->LDS, 16B per lane; LDS dest must be wave-uniform base (+lane*16 by HW)
__device__ __forceinline__ void g2l16(const void* g, void* l) {
    __builtin_amdgcn_global_load_lds(
        (const __attribute__((address_space(1))) unsigned int*)g,
        (__attribute__((address_space(3))) unsigned int*)l,
        16, 0, 0);
}

// ---------- kernel 2: weight transpose + convert: wT[n][k] = bf16(w[k][n]) ----------
__global__ __launch_bounds__(256) void wtrans_kernel(
    const float* __restrict__ w0, const float* __restrict__ w1,
    const float* __restrict__ w2, const float* __restrict__ w3,
    unsigned short* __restrict__ wt)
{
    const int z = blockIdx.z;
    const float* w = z == 0 ? w0 : z == 1 ? w1 : z == 2 ? w2 : w3;
    __shared__ float t[32][33];
    const int bx = blockIdx.x * 32;   // n base
    const int by = blockIdx.y * 32;   // k base
    const int tx = threadIdx.x, ty = threadIdx.y;   // (32, 8)
    #pragma unroll
    for (int i = 0; i < 4; ++i)
        t[ty + i*8][tx] = w[(size_t)(by + ty + i*8) * DMODEL + bx + tx];  // t[krel][nrel]
    __syncthreads();
    unsigned short* o = wt + (size_t)z * ((size_t)DMODEL * DMODEL);
    #pragma unroll
    for (int i = 0; i < 4; ++i) {
        int nrel = ty + i*8, krel = tx;
        o[(size_t)(bx + nrel) * DMODEL + by + krel] = f2b(t[krel][nrel]);
    }
}

// ---------- kernel 3: fused QKV GEMM, full T14 (A and B reg-staged) ----------
// C = bf16(A_f32)[M,K] * Bt[N,K]^T + bias. 128x128 tile, BK=64, 4 waves.
// BOTH operands reg-staged; next tile's loads issued right after the write
// barrier so no vmem op is outstanding at any barrier (the old g2l16-B path
// drained vmcnt(0) at every __syncthreads — ~350 cyc/step exposed).
__global__ __launch_bounds__(256, 3) void gemm_qkv_kernel(
    const float* __restrict__ qf, const float* __restrict__ kf, const float* __restrict__ vf,
    const unsigned short* __restrict__ wtbase,
    const float* __restrict__ b0, const float* __restrict__ b1, const float* __restrict__ b2,
    unsigned short* __restrict__ qh, unsigned short* __restrict__ kh,
    unsigned short* __restrict__ vT)
{
    const int mode = blockIdx.z;
    const float* Af = mode == 0 ? qf : mode == 1 ? kf : vf;
    const unsigned short* Bt = wtbase + (size_t)mode * ((size_t)DMODEL * DMODEL);
    const float* bias = mode == 0 ? b0 : mode == 1 ? b1 : b2;

    __shared__ unsigned short As[128 * 64];
    __shared__ unsigned short Bs[128 * 64];

    const int tid = threadIdx.x;
    const int lane = tid & 63, wid = tid >> 6;
    const int ll = lane & 15, lg = lane >> 4;
    const int mb = blockIdx.x * 128, nb = blockIdx.y * 128;
    const int wr = wid >> 1, wc = wid & 1;

    f32x4 acc[4][4] = {};
    f32x4 stgA[8];
    u32x4 stgB[4];

    auto issueA = [&](int kb) {
        #pragma unroll
        for (int it = 0; it < 4; ++it) {
            int ci = it * 256 + tid;
            int r = ci >> 3;
            int cbs = ((ci & 7) * 16) ^ ((r & 7) << 4);      // bf16 byte off in 128B row
            const float* src = Af + (size_t)(mb + r) * DMODEL + kb + (cbs >> 1);
            stgA[2 * it]     = *(const f32x4*)src;
            stgA[2 * it + 1] = *(const f32x4*)(src + 4);
        }
    };
    auto issueB = [&](int kb) {
        #pragma unroll
        for (int it = 0; it < 4; ++it) {
            int ci = it * 256 + tid;
            int r = ci >> 3;
            int cbs = ((ci & 7) * 16) ^ ((r & 7) << 4);
            stgB[it] = *(const u32x4*)((const char*)Bt + ((size_t)(nb + r) * DMODEL + kb) * 2 + cbs);
        }
    };

    issueA(0);
    issueB(0);

    for (int kb = 0; kb < DMODEL; kb += 64) {
        __syncthreads();                    // all waves done reading LDS
        #pragma unroll
        for (int it = 0; it < 4; ++it) {    // cvt + write A chunk to linear slot
            u32x4 w = { cvtpk(stgA[2*it][0],   stgA[2*it][1]),
                        cvtpk(stgA[2*it][2],   stgA[2*it][3]),
                        cvtpk(stgA[2*it+1][0], stgA[2*it+1][1]),
                        cvtpk(stgA[2*it+1][2], stgA[2*it+1][3]) };
            *(u32x4*)((char*)As + (it * 256 + tid) * 16) = w;
        }
        #pragma unroll
        for (int it = 0; it < 4; ++it)      // write B chunk (same slot map as g2l16)
            *(u32x4*)((char*)Bs + (it * 256 + tid) * 16) = stgB[it];
        __syncthreads();                    // LDS writes visible (lgkm only)
        if (kb + 64 < DMODEL) { issueA(kb + 64); issueB(kb + 64); }   // fly over compute

        #pragma unroll
        for (int kk = 0; kk < 2; ++kk) {
            s16x8 af[4], bfr[4];
            #pragma unroll
            for (int m = 0; m < 4; ++m) {
                int row = wr * 64 + m * 16 + ll;
                int cbyte = (kk * 64 + lg * 16) ^ ((row & 7) << 4);
                af[m] = *(const s16x8*)((const char*)As + row * 128 + cbyte);
            }
            #pragma unroll
            for (int n = 0; n < 4; ++n) {
                int row = wc * 64 + n * 16 + ll;
                int cbyte = (kk * 64 + lg * 16) ^ ((row & 7) << 4);
                bfr[n] = *(const s16x8*)((const char*)Bs + row * 128 + cbyte);
            }
            #pragma unroll
            for (int m = 0; m < 4; ++m)
                #pragma unroll
                for (int n = 0; n < 4; ++n)
                    acc[m][n] = __builtin_amdgcn_mfma_f32_16x16x32_bf16(af[m], bfr[n], acc[m][n], 0, 0, 0);
        }
    }

    // epilogue: col = lane&15, row = (lane>>4)*4 + r
    #pragma unroll
    for (int m = 0; m < 4; ++m) {
        int grow0 = mb + wr * 64 + m * 16 + lg * 4;
        #pragma unroll
        for (int n = 0; n < 4; ++n) {
            int col = nb + wc * 64 + n * 16 + ll;
            float bc = bias[col];
            f32x4 v = acc[m][n];
            if (mode == 2) {
                int b = grow0 >> 11, s0 = grow0 & 2047;
                int h = col >> 6, d = col & 63;
                ushort4 pk;
                pk.x = f2b(v[0] + bc); pk.y = f2b(v[1] + bc);
                pk.z = f2b(v[2] + bc); pk.w = f2b(v[3] + bc);
                *(ushort4*)(vT + ((size_t)((b * NHEAD + h) * 64 + d) << 11) + s0) = pk;
            } else {
                unsigned short* dst = (mode == 0) ? qh : kh;
                float scl = (mode == 0) ? 0.125f * 1.44269504089f : 1.0f;
                int b = grow0 >> 11, s0 = grow0 & 2047;
                int h = col >> 6, d = col & 63;
                #pragma unroll
                for (int r = 0; r < 4; ++r)
                    dst[((size_t)(b * NHEAD + h) * SEQ + s0 + r) * 64 + d] = f2b((v[r] + bc) * scl);
            }
        }
    }
}

// ---------- kernel 5: O-projection GEMM, full T14 (A and B reg-staged) ----------
__global__ __launch_bounds__(256, 2) void gemm_o_kernel(
    const unsigned short* __restrict__ Ap,
    const unsigned short* __restrict__ Bt,
    const float* __restrict__ bias,
    float* __restrict__ outF)
{
    constexpr int TM = 64;
    constexpr int WM = TM / 2;
    constexpr int MT = WM / 16;      // 2

    __shared__ unsigned short As[TM * 64];
    __shared__ unsigned short Bs[128 * 64];

    const int tid = threadIdx.x;
    const int lane = tid & 63, wid = tid >> 6;
    const int ll = lane & 15, lg = lane >> 4;
    const int mb = blockIdx.x * TM, nb = blockIdx.y * 128;
    const int wr = wid >> 1, wc = wid & 1;

    f32x4 acc[MT][4] = {};
    u32x4 stgA[2], stgB[4];

    auto issueA = [&](int kb) {
        #pragma unroll
        for (int it = 0; it < 2; ++it) {
            int ci = it * 256 + tid;
            int r = ci >> 3;
            int cbs = ((ci & 7) * 16) ^ ((r & 7) << 4);
            stgA[it] = *(const u32x4*)((const char*)Ap + ((size_t)(mb + r) * DMODEL + kb) * 2 + cbs);
        }
    };
    auto issueB = [&](int kb) {
        #pragma unroll
        for (int it = 0; it < 4; ++it) {
            int ci = it * 256 + tid;
            int r = ci >> 3;
            int cbs = ((ci & 7) * 16) ^ ((r & 7) << 4);
            stgB[it] = *(const u32x4*)((const char*)Bt + ((size_t)(nb + r) * DMODEL + kb) * 2 + cbs);
        }
    };

    issueA(0);
    issueB(0);

    for (int kb = 0; kb < DMODEL; kb += 64) {
        __syncthreads();
        #pragma unroll
        for (int it = 0; it < 2; ++it)
            *(u32x4*)((char*)As + (it * 256 + tid) * 16) = stgA[it];
        #pragma unroll
        for (int it = 0; it < 4; ++it)
            *(u32x4*)((char*)Bs + (it * 256 + tid) * 16) = stgB[it];
        __syncthreads();
        if (kb + 64 < DMODEL) { issueA(kb + 64); issueB(kb + 64); }

        #pragma unroll
        for (int kk = 0; kk < 2; ++kk) {
            s16x8 af[MT], bfr[4];
            #pragma unroll
            for (int m = 0; m < MT; ++m) {
                int row = wr * WM + m * 16 + ll;
                int cbyte = (kk * 64 + lg * 16) ^ ((row & 7) << 4);
                af[m] = *(const s16x8*)((const char*)As + row * 128 + cbyte);
            }
            #pragma unroll
            for (int n = 0; n < 4; ++n) {
                int row = wc * 64 + n * 16 + ll;
                int cbyte = (kk * 64 + lg * 16) ^ ((row & 7) << 4);
                bfr[n] = *(const s16x8*)((const char*)Bs + row * 128 + cbyte);
            }
            #pragma unroll
            for (int m = 0; m < MT; ++m)
                #pragma unroll
                for (int n = 0; n < 4; ++n)
                    acc[m][n] = __builtin_amdgcn_mfma_f32_16x16x32_bf16(af[m], bfr[n], acc[m][n], 0, 0, 0);
        }
    }

    #pragma unroll
    for (int m = 0; m < MT; ++m) {
        int grow0 = mb + wr * WM + m * 16 + lg * 4;
        #pragma unroll
        for (int n = 0; n < 4; ++n) {
            int col = nb + wc * 64 + n * 16 + ll;
            float bc = bias[col];
            f32x4 v = acc[m][n];
            #pragma unroll
            for (int r = 0; r < 4; ++r)
                outF[(size_t)(grow0 + r) * DMODEL + col] = v[r] + bc;
        }
    }
}

// ---------- kernel 4: causal flash attention (unchanged from R12, 43 µs) ----------
__global__ __launch_bounds__(256, 3) void attn_kernel(
    const unsigned short* __restrict__ qh, const unsigned short* __restrict__ kh,
    const unsigned short* __restrict__ vT, unsigned short* __restrict__ attnout)
{
    const int bid = blockIdx.x;
    const int bh = bid & 31;
    const int j  = 31 - (bid >> 5);     // heavy-first (LPT)
    const int qb = j * 64;
    const int nss = (j >> 1) + 1;       // super-steps of 128 cols

    const unsigned short* Q = qh + (size_t)bh * (SEQ * 64);
    const unsigned short* K = kh + (size_t)bh * (SEQ * 64);
    const unsigned short* V = vT + (size_t)bh * (64 * SEQ);   // [64 d][2048 s]

    __shared__ char lds[32768];
    char* Kb = lds;            // K super-tile [128 k][64 d], 128B rows, swz (k&7)<<4
    char* Vb = lds + 16384;    // V super-tile [64 d][128 k], 256B rows, swz (d&15)<<4

    const int tid = threadIdx.x, lane = tid & 63, wid = tid >> 6;
    const int l31 = lane & 31, hi = lane >> 5;
    const int qhf = wid & 1;            // q-half
    const int par = wid >> 1;           // k-parity (col half)
    const int qrow = qb + qhf * 32 + l31;

    s16x8 aq[4];
    {
        const unsigned short* qp = Q + (size_t)qrow * 64 + hi * 8;
        #pragma unroll
        for (int u = 0; u < 4; ++u)
            aq[u] = *(const s16x8*)(qp + u * 16);
    }

    f32x16 oc0 = {}, oc1 = {};     // O[q=crow(r,hi)][d]: d-halves 0..31 / 32..63
    float mrow = -1e30f, lrow = 0.f;

    u32x4 stg[8];
    auto issue = [&](int kb) {
        #pragma unroll
        for (int it = 0; it < 4; ++it) {          // K: 128 rows x 128B
            int ci = it * 256 + tid;
            int r = ci >> 3;
            int sb = ((ci & 7) * 16) ^ ((r & 7) << 4);
            stg[it] = *(const u32x4*)((const char*)K + ((size_t)(kb + r) * 64) * 2 + sb);
        }
        #pragma unroll
        for (int it = 0; it < 4; ++it) {          // V: 64 rows x 256B
            int ci = it * 256 + tid;
            int d = ci >> 4;
            int sb = ((ci & 15) * 16) ^ ((d & 15) << 4);
            stg[4 + it] = *(const u32x4*)((const char*)V + (size_t)d * (SEQ * 2) + (size_t)kb * 2 + sb);
        }
    };

    issue(0);

    for (int ss = 0; ss < nss; ++ss) {
        const int kb = ss * 128;
        __syncthreads();                // all waves done reading previous tile
        #pragma unroll
        for (int it = 0; it < 8; ++it)  // regs -> LDS (compiler waits vmcnt here)
            *(u32x4*)(lds + it * 4096 + tid * 16) = stg[it];
        if (ss + 1 < nss) issue(kb + 128);   // in flight across this step's compute
        __syncthreads();                // tile visible

        const int rb = par * 64;
        f32x16 p0 = {}, p1 = {};
        __builtin_amdgcn_s_setprio(1);
        #pragma unroll
        for (int u = 0; u < 4; ++u) {
            int r0 = rb + l31, r1 = rb + 32 + l31;
            s16x8 k0 = *(const s16x8*)(Kb + r0 * 128 + (((u * 32 + hi * 16)) ^ ((r0 & 7) << 4)));
            s16x8 k1 = *(const s16x8*)(Kb + r1 * 128 + (((u * 32 + hi * 16)) ^ ((r1 & 7) << 4)));
            p0 = __builtin_amdgcn_mfma_f32_32x32x16_bf16(k0, aq[u], p0, 0, 0, 0);
            p1 = __builtin_amdgcn_mfma_f32_32x32x16_bf16(k1, aq[u], p1, 0, 0, 0);
        }
        __builtin_amdgcn_s_setprio(0);

        if (ss == nss - 1) {           // diagonal super-step: mask k > q
            const int pabs = kb + rb;
            #pragma unroll
            for (int r = 0; r < 16; ++r) {
                int rl = (r & 3) + 8 * (r >> 2) + 4 * hi;
                if (pabs + rl > qrow)      p0[r] = -1e30f;
                if (pabs + 32 + rl > qrow) p1[r] = -1e30f;
            }
        }

        float tm[8];
        #pragma unroll
        for (int i = 0; i < 8; ++i)
            tm[i] = fmaxf(fmaxf(p0[i], p0[i + 8]), fmaxf(p1[i], p1[i + 8]));
        float mx = fmaxf(fmaxf(fmaxf(tm[0], tm[1]), fmaxf(tm[2], tm[3])),
                         fmaxf(fmaxf(tm[4], tm[5]), fmaxf(tm[6], tm[7])));
        mx = fmaxf(mx, __shfl_xor(mx, 32, 64));

        if (!__all(mx - mrow <= 8.0f)) {
            float mnew = fmaxf(mrow, mx);
            float sclf = EXP2(mrow - mnew);   // factor for q-row = l31
            lrow *= sclf;
            #pragma unroll
            for (int r = 0; r < 16; ++r) {    // oc[r] is q-row crow(r,hi)
                int src = (r & 3) + 8 * (r >> 2) + 4 * hi;
                float sf = __shfl(sclf, src, 64);
                oc0[r] *= sf;
                oc1[r] *= sf;
            }
            mrow = mnew;
        }

        #pragma unroll
        for (int i = 0; i < 16; ++i) { p0[i] = EXP2(p0[i] - mrow); p1[i] = EXP2(p1[i] - mrow); }

        float s8[8];
        #pragma unroll
        for (int i = 0; i < 8; ++i)
            s8[i] = (p0[i] + p0[i + 8]) + (p1[i] + p1[i + 8]);
        float ts = ((s8[0] + s8[1]) + (s8[2] + s8[3])) + ((s8[4] + s8[5]) + (s8[6] + s8[7]));
        ts += __shfl_xor(ts, 32, 64);
        lrow += ts;

        s16x8 pa[4];
        #pragma unroll
        for (int g = 0; g < 4; ++g) {
            const f32x16 pv = (g < 2) ? p0 : p1;
            const int o = (g & 1) * 8;
            unsigned a0 = cvtpk(pv[o + 0], pv[o + 1]);
            unsigned a1 = cvtpk(pv[o + 2], pv[o + 3]);
            unsigned b0 = cvtpk(pv[o + 4], pv[o + 5]);
            unsigned b1 = cvtpk(pv[o + 6], pv[o + 7]);
            asm("v_permlane32_swap_b32 %0, %1" : "+v"(a0), "+v"(b0));
            asm("v_permlane32_swap_b32 %0, %1" : "+v"(a1), "+v"(b1));
            u32x4 t4 = {a0, a1, b0, b1};
            pa[g] = __builtin_bit_cast(s16x8, t4);
        }

        __builtin_amdgcn_s_setprio(1);
        #pragma unroll
        for (int s = 0; s < 4; ++s) {
            int cbyte = par * 128 + s * 32 + hi * 16;
            int d0 = l31, d1 = 32 + l31;
            s16x8 vb0 = *(const s16x8*)(Vb + d0 * 256 + (cbyte ^ ((d0 & 15) << 4)));
            s16x8 vb1 = *(const s16x8*)(Vb + d1 * 256 + (cbyte ^ ((d1 & 15) << 4)));
            oc0 = __builtin_amdgcn_mfma_f32_32x32x16_bf16(pa[s], vb0, oc0, 0, 0, 0);
            oc1 = __builtin_amdgcn_mfma_f32_32x32x16_bf16(pa[s], vb1, oc1, 0, 0, 0);
        }
        __builtin_amdgcn_s_setprio(0);
    }

    // ---- cross-parity merge via LDS (exact flash combine) ----
    __syncthreads();
    float* Os = (float*)(void*)lds + qhf * 2048;   // [32 q][64 d] per q-half (16KB)
    float* ms = (float*)(void*)(lds + 16384);      // [64] m1 per (qhf,row)
    float* ls = ms + 64;                           // [64] l1
    if (par == 1) {
        if (hi == 0) { ms[qhf * 32 + l31] = mrow; ls[qhf * 32 + l31] = lrow; }
        #pragma unroll
        for (int r = 0; r < 16; ++r) {
            int rl = (r & 3) + 8 * (r >> 2) + 4 * hi;
            Os[rl * 64 + l31]      = oc0[r];
            Os[rl * 64 + 32 + l31] = oc1[r];
        }
    }
    __syncthreads();
    if (par == 0) {
        float m1 = ms[qhf * 32 + l31], l1 = ls[qhf * 32 + l31];
        float M  = fmaxf(mrow, m1);
        float wa = EXP2(mrow - M);
        float wb = EXP2(m1 - M);       // = 0 when parity-1 never saw valid cols
        float inv = 1.0f / (lrow * wa + l1 * wb);
        const int b = bh >> 4, h = bh & 15;
        #pragma unroll
        for (int r = 0; r < 16; ++r) {
            int rl = (r & 3) + 8 * (r >> 2) + 4 * hi;
            float ar = __shfl(wa, rl, 64);
            float br = __shfl(wb, rl, 64);
            float ir = __shfl(inv, rl, 64);
            size_t base = ((size_t)(b * SEQ + qb + qhf * 32 + rl) << 10) + h * 64;
            attnout[base + l31]      = f2b((oc0[r] * ar + Os[rl * 64 + l31]      * br) * ir);
            attnout[base + 32 + l31] = f2b((oc1[r] * ar + Os[rl * 64 + 32 + l31] * br) * ir);
        }
    }
}

// ---------- launch ----------
extern "C" void kernel_launch(void* const* d_in, const int* in_sizes, int n_in,
                              void* d_out, int out_size, void* d_ws, size_t ws_size,
                              hipStream_t stream) {
    const float* query = (const float*)d_in[0];
    const float* key   = (const float*)d_in[1];
    const float* value = (const float*)d_in[2];
    // d_in[3] = mask: causal, recomputed analytically
    const float* wq = (const float*)d_in[4];
    const float* bq = (const float*)d_in[5];
    const float* wk = (const float*)d_in[6];
    const float* bk = (const float*)d_in[7];
    const float* wv = (const float*)d_in[8];
    const float* bv = (const float*)d_in[9];
    const float* wo = (const float*)d_in[10];
    const float* bo = (const float*)d_in[11];
    float* out = (float*)d_out;

    char* ws = (char*)d_ws;
    unsigned short* xb  = (unsigned short*)ws;                 // [4096][1024] bf16 attn-out
    unsigned short* wt  = (unsigned short*)(ws + 25165824);    // [4][1024][1024] bf16 (wT: q,k,v,o)
    unsigned short* qhp = (unsigned short*)(ws + 33554432);    // [2][16][2048][64] bf16 (scaled)
    unsigned short* khp = (unsigned short*)(ws + 41943040);    // [2][16][2048][64] bf16
    unsigned short* vTp = (unsigned short*)(ws + 50331648);    // [2][16][64][2048] bf16
    // total ws use: 58,720,256 B

    wtrans_kernel<<<dim3(32, 32, 4), dim3(32, 8), 0, stream>>>(wq, wk, wv, wo, wt);
    gemm_qkv_kernel<<<dim3(32, 8, 3), 256, 0, stream>>>(query, key, value, wt,
                                                        bq, bk, bv, qhp, khp, vTp);
    attn_kernel<<<dim3(1024), 256, 0, stream>>>(qhp, khp, vTp, xb);
    gemm_o_kernel<<<dim3(64, 8), 256, 0, stream>>>(xb, wt + 3 * (size_t)(DMODEL * DMODEL), bo, out);
}